// Round 14
// baseline (271.046 us; speedup 1.0000x reference)
//
#include <hip/hip_runtime.h>
#include <hip/hip_bf16.h>

#define Bb 256
#define Ll 200
#define Dd 128
#define BL (Bb*Ll)
#define KVS 266   // kvL row stride in shorts: 133 dwords (odd) -> conflict-free b128 row reads

typedef __hip_bfloat16 bf16;
typedef __attribute__((ext_vector_type(8))) short short8;
typedef __attribute__((ext_vector_type(4))) unsigned short ushort4v;
typedef __attribute__((ext_vector_type(4))) float floatx4;

__device__ __forceinline__ float b2f(bf16 v) { return __bfloat162float(v); }
__device__ __forceinline__ bf16  f2b(float v) { return __float2bfloat16(v); }
__device__ __forceinline__ float us2f(unsigned short u) { return __uint_as_float(((unsigned)u) << 16); }
__device__ __forceinline__ unsigned short f2us(float v) { bf16 t = f2b(v); return *(unsigned short*)&t; }
__device__ __forceinline__ float ldf(const void* p, int i, int f32) {
  return f32 ? ((const float*)p)[i] : b2f(((const bf16*)p)[i]);
}
// dtype probe: uniform(-.088,.088) bf16 never has exp>=0x7F; f32 mantissa halves do ~50%.
__device__ __forceinline__ int detect_f32(const unsigned short* __restrict__ w) {
  unsigned short u = w[threadIdx.x & 63];
  return (__ballot(((u >> 7) & 0xFF) >= 0x7F) != 0ull) ? 1 : 0;
}
// async global->LDS DMA, 16B per lane; LDS dest = wave-uniform base + lane*16
__device__ __forceinline__ void load_lds16(const void* g, void* l) {
  __builtin_amdgcn_global_load_lds((const __attribute__((address_space(1))) unsigned int*)g,
                                   (__attribute__((address_space(3))) unsigned int*)l, 16, 0, 0);
}
// gather one 8-elem chunk (cols 8g..8g+7) of emb row `it`, dtype-aware, as bf16x8 (vectorized)
__device__ __forceinline__ short8 emb_chunk8(const void* __restrict__ emb, int it, int g, int f32) {
  short8 o;
  if (f32) {
    const float4* e = (const float4*)((const float*)emb + (size_t)it * 128 + g * 8);
    float4 a = e[0], b = e[1];
    o[0] = (short)f2us(a.x); o[1] = (short)f2us(a.y); o[2] = (short)f2us(a.z); o[3] = (short)f2us(a.w);
    o[4] = (short)f2us(b.x); o[5] = (short)f2us(b.y); o[6] = (short)f2us(b.z); o[7] = (short)f2us(b.w);
  } else {
    o = ((const short8*)((const bf16*)emb + (size_t)it * 128))[g];
  }
  return o;
}

// ---------------------------------------------------------------- K01: graph build (blocks 0..255) + pack (rest)
struct PackP {
  const void *W_ei,*W_eo,*w_ih,*w_hh,*Wk,*Wv,*Wqp,*Wop,*W1p,*W2p,*pos;
  const void *b_ei,*b_eo,*b_ih,*b_hh,*bk,*bv,*bqp,*bop,*b1p,*b2p,*biah,*boah;
  const void *ln1g,*ln1b,*ln2g,*ln2b,*lnfg,*lnfb;
  bf16 *cWhe,*cWih,*cWhh,*cWkv,*cWq,*cWo,*cW1,*cW2,*cPos;
  float *bias_he,*bias_gi,*bias_gh,*bias_kv,*cbq,*cbo,*cb1,*cb2,*cbiah,*cboah,*cln;
  const int* seqs;
  int *alias_g, *items_g; float *rin_g, *rout_g; unsigned *adj_g, *adjT_g;
};
__global__ __launch_bounds__(256) void k01(PackP p) {
  __shared__ alignas(16) int s[Ll];
  __shared__ int al[Ll], its[Ll];
  __shared__ alignas(4) unsigned char isf[Ll];
  __shared__ unsigned adjL[Ll*8], adjTL[Ll*8];
  if (blockIdx.x >= Bb) {
    int idx = (blockIdx.x - Bb) * 256 + threadIdx.x;       // < 306944
    int f32 = detect_f32((const unsigned short*)p.W_ei);
    if (idx < 131072) {
      if (idx < 32768) {
        int r = idx >> 7, c = idx & 127;
        p.cWhe[idx] = f2b(r < 128 ? ldf(p.W_ei, r*128+c, f32) : ldf(p.W_eo, (r-128)*128+c, f32));
      } else p.cWih[idx-32768] = f2b(ldf(p.w_ih, idx-32768, f32));
    } else if (idx < 278528) {
      if (idx < 180224)      p.cWhh[idx-131072] = f2b(ldf(p.w_hh, idx-131072, f32));
      else if (idx < 212992) {
        int i = idx - 180224; int r = i >> 7, c = i & 127;
        p.cWkv[i] = f2b(r < 128 ? ldf(p.Wk, r*128+c, f32) : ldf(p.Wv, (r-128)*128+c, f32));
      }
      else if (idx < 229376) p.cWq[idx-212992] = f2b(ldf(p.Wqp, idx-212992, f32));
      else if (idx < 245760) p.cWo[idx-229376] = f2b(ldf(p.Wop, idx-229376, f32));
      else if (idx < 262144) p.cW1[idx-245760] = f2b(ldf(p.W1p, idx-245760, f32));
      else                   p.cW2[idx-262144] = f2b(ldf(p.W2p, idx-262144, f32));
    } else if (idx < 304128) {
      p.cPos[idx-278528] = f2b(ldf(p.pos, idx-278528, f32));
    } else {
      int j = idx - 304128;                          // < 2816
      if      (j < 256)  p.bias_he[j]     = (j<128) ? ldf(p.b_ei,j,f32) : ldf(p.b_eo,j-128,f32);
      else if (j < 640)  p.bias_gi[j-256] = ldf(p.b_ih, j-256, f32);
      else if (j < 1024) p.bias_gh[j-640] = ldf(p.b_hh, j-640, f32);
      else if (j < 1280) { int c=j-1024; p.bias_kv[c] = (c<128)? ldf(p.bk,c,f32): ldf(p.bv,c-128,f32); }
      else if (j < 1408) p.cbq[j-1280]   = ldf(p.bqp, j-1280, f32);
      else if (j < 1536) p.cbo[j-1408]   = ldf(p.bop, j-1408, f32);
      else if (j < 1664) p.cb1[j-1536]   = ldf(p.b1p, j-1536, f32);
      else if (j < 1792) p.cb2[j-1664]   = ldf(p.b2p, j-1664, f32);
      else if (j < 1920) p.cbiah[j-1792] = ldf(p.biah, j-1792, f32);
      else if (j < 2048) p.cboah[j-1920] = ldf(p.boah, j-1920, f32);
      else {
        int i = j - 2048, g = i >> 7, c2 = i & 127;
        const void* s6 = g==0?p.ln1g: g==1?p.ln1b: g==2?p.ln2g: g==3?p.ln2b: g==4?p.lnfg: p.lnfb;
        p.cln[i] = ldf(s6, c2, f32);
      }
    }
    return;
  }
  // ---- graph part (one block per batch row), int4-vectorized inner loops
  int b = blockIdx.x, t = threadIdx.x;
  if (t < Ll) s[t] = p.seqs[b*Ll + t];
  for (int i = t; i < Ll*8; i += 256) { adjL[i] = 0u; adjTL[i] = 0u; }
  __syncthreads();
  const int4* s4 = (const int4*)s;
  if (t < Ll) {
    int v = s[t]; int dup = 0;
    int nb = t >> 2;
    for (int j4 = 0; j4 < nb; j4++) {
      int4 sv = s4[j4];
      dup |= (sv.x==v) | (sv.y==v) | (sv.z==v) | (sv.w==v);
    }
    for (int j = nb*4; j < t; j++) dup |= (s[j]==v);
    isf[t] = dup ? 0 : 1; its[t] = 0;
  }
  __syncthreads();
  const unsigned* isfw = (const unsigned*)isf;
  if (t < Ll) {
    int v = s[t], r = 0;
    for (int j4 = 0; j4 < Ll/4; j4++) {
      int4 sv = s4[j4];
      unsigned fw = isfw[j4];
      r += ((fw & 0xffu)       && sv.x < v);
      r += ((fw & 0xff00u)     && sv.y < v);
      r += ((fw & 0xff0000u)   && sv.z < v);
      r += ((fw & 0xff000000u) && sv.w < v);
    }
    al[t] = r;
  }
  __syncthreads();
  if (t < Ll && isf[t]) its[al[t]] = s[t];
  if (t < Ll-1 && s[t+1] > 0) {
    int u = al[t], v = al[t+1];
    atomicOr(&adjL [u*8 + (v >> 5)], 1u << (v & 31));
    atomicOr(&adjTL[v*8 + (u >> 5)], 1u << (u & 31));
  }
  __syncthreads();
  if (t < Ll) {
    int od = 0, id = 0;
    for (int wd = 0; wd < 7; wd++) { od += __popc(adjL[t*8+wd]); id += __popc(adjTL[t*8+wd]); }
    p.rout_g [b*Ll + t] = 1.0f / (float)max(od, 1);
    p.rin_g  [b*Ll + t] = 1.0f / (float)max(id, 1);
    p.alias_g[b*Ll + t] = al[t];
    p.items_g[b*Ll + t] = its[t];
  }
  for (int i = t; i < Ll*8; i += 256) { p.adj_g[b*Ll*8 + i] = adjL[i]; p.adjT_g[b*Ll*8 + i] = adjTL[i]; }
}

// ---------------------------------------------------------------- GEMM-HE v2: A gathered ONCE, loop over 5 n-tiles
__global__ __launch_bounds__(256) void gemm_he2(const void* __restrict__ emb, const int* __restrict__ items_g,
    const bf16* __restrict__ W, const float* __restrict__ bias,
    bf16* __restrict__ out_lo, int Nlo, bf16* __restrict__ out_hi, int Nhi, int split)
{
  __shared__ short As[128*128];                 // 32 KB
  __shared__ short Ws[128*128];                 // 32 KB
  int t = threadIdx.x;
  int wave = t >> 6, lane = t & 63;
  int q = lane >> 4, mr = lane & 15;
  int wm = wave & 1, wn = wave >> 1;
  int m0 = blockIdx.x * 128;
  int f32 = detect_f32((const unsigned short*)emb);
  {
    int r = t >> 1, half = t & 1;
    int it = items_g[m0 + r];
#pragma unroll
    for (int g8 = 0; g8 < 8; g8++) {
      int g = half*8 + g8;
      short8 o = emb_chunk8(emb, it, g, f32);
      *(short8*)&As[r*128 + (g ^ (r & 15))*8] = o;
    }
  }
  int srow = lane >> 4, c16 = lane & 15;
  for (int nt = 0; nt < 5; nt++) {
    int n0 = nt * 128;
#pragma unroll
    for (int i = 0; i < 8; i++) {
      int seg = wave*8 + i;
      int r = seg*4 + srow;
      int gch = c16 ^ (r & 15);
      load_lds16(W + (size_t)(n0 + r) * 128 + gch*8, &Ws[seg*512]);
    }
    __syncthreads();
    floatx4 acc[4][4] = {};
#pragma unroll
    for (int kk = 0; kk < 4; kk++) {
      short8 af[4], wf[4];
#pragma unroll
      for (int i = 0; i < 4; i++) {
        int row = wm*64 + i*16 + mr;
        af[i] = *(const short8*)(&As[row*128 + ((kk*4+q) ^ (row&15))*8]);
      }
#pragma unroll
      for (int j = 0; j < 4; j++) {
        int row = wn*64 + j*16 + mr;
        wf[j] = *(const short8*)(&Ws[row*128 + ((kk*4+q) ^ (row&15))*8]);
      }
#pragma unroll
      for (int i = 0; i < 4; i++)
#pragma unroll
        for (int j = 0; j < 4; j++)
          acc[i][j] = __builtin_amdgcn_mfma_f32_16x16x32_bf16(wf[j], af[i], acc[i][j], 0, 0, 0);
    }
#pragma unroll
    for (int j = 0; j < 4; j++) {
      int ng = n0 + wn*64 + j*16 + q*4;
      floatx4 bs = *(const floatx4*)(bias + ng);
      bf16* outp; int col, stride;
      if (ng < split) { outp = out_lo; col = ng; stride = Nlo; }
      else            { outp = out_hi; col = ng - split; stride = Nhi; }
#pragma unroll
      for (int i = 0; i < 4; i++) {
        int m = m0 + wm*64 + i*16 + mr;
        ushort4v o;
#pragma unroll
        for (int e = 0; e < 4; e++) o[e] = f2us(acc[i][j][e] + bs[e]);
        *(ushort4v*)(outp + (size_t)m * stride + col) = o;
      }
    }
    if (nt + 1 < 5) __syncthreads();
  }
}

// ---------------------------------------------------------------- MFMA GEMM v6 (used for gi: K=256)
template<int K>
__global__ __launch_bounds__(256) void gemm6(const bf16* __restrict__ A, const bf16* __restrict__ W,
    const float* __restrict__ bias,
    bf16* __restrict__ out_lo, int Nlo, bf16* __restrict__ out_hi, int Nhi, int split)
{
  __shared__ short As[128*128];                 // 32 KB
  __shared__ short Ws[128*128];                 // 32 KB
  int t = threadIdx.x;
  int wave = t >> 6, lane = t & 63;
  int q = lane >> 4, mr = lane & 15;
  int wm = wave & 1, wn = wave >> 1;
  int m0 = blockIdx.x * 128, n0 = blockIdx.y * 128;
  int srow = lane >> 4;
  int c16 = lane & 15;
  floatx4 acc[4][4] = {};
  for (int k0 = 0; k0 < K; k0 += 128) {
#pragma unroll
    for (int i = 0; i < 8; i++) {
      int seg = wave*8 + i;
      int r = seg*4 + srow;
      int gch = c16 ^ (r & 15);
      load_lds16(A + (size_t)(m0 + r) * K + k0 + gch*8, &As[seg*512]);
      load_lds16(W + (size_t)(n0 + r) * K + k0 + gch*8, &Ws[seg*512]);
    }
    __syncthreads();
#pragma unroll
    for (int kk = 0; kk < 4; kk++) {
      short8 af[4], wf[4];
#pragma unroll
      for (int i = 0; i < 4; i++) {
        int row = wm*64 + i*16 + mr;
        af[i] = *(const short8*)(&As[row*128 + ((kk*4+q) ^ (row&15))*8]);
      }
#pragma unroll
      for (int j = 0; j < 4; j++) {
        int row = wn*64 + j*16 + mr;
        wf[j] = *(const short8*)(&Ws[row*128 + ((kk*4+q) ^ (row&15))*8]);
      }
#pragma unroll
      for (int i = 0; i < 4; i++)
#pragma unroll
        for (int j = 0; j < 4; j++)
          acc[i][j] = __builtin_amdgcn_mfma_f32_16x16x32_bf16(wf[j], af[i], acc[i][j], 0, 0, 0);
    }
    if (k0 + 128 < K) __syncthreads();
  }
#pragma unroll
  for (int j = 0; j < 4; j++) {
    int ng = n0 + wn*64 + j*16 + q*4;
    floatx4 bs = *(const floatx4*)(bias + ng);
    bf16* outp; int col, stride;
    if (ng < split) { outp = out_lo; col = ng; stride = Nlo; }
    else            { outp = out_hi; col = ng - split; stride = Nhi; }
#pragma unroll
    for (int i = 0; i < 4; i++) {
      int m = m0 + wm*64 + i*16 + mr;
      ushort4v o;
#pragma unroll
      for (int e = 0; e < 4; e++) o[e] = f2us(acc[i][j][e] + bs[e]);
      *(ushort4v*)(outp + (size_t)m * stride + col) = o;
    }
  }
}

// ---------------------------------------------------------------- K3: sparse graph aggregation (one wave per node)
__global__ __launch_bounds__(256) void k3_agg(const bf16* __restrict__ he,
    const unsigned* __restrict__ adj_g, const unsigned* __restrict__ adjT_g,
    const float* __restrict__ rin_g, const float* __restrict__ rout_g,
    const float* __restrict__ cbiah, const float* __restrict__ cboah, bf16* __restrict__ hio)
{
  int b = blockIdx.x / 25, chunk = blockIdx.x % 25;
  int wave = threadIdx.x >> 6, lane = threadIdx.x & 63;
  bool isIn = lane < 32;
  int c = isIn ? 4*lane : 128 + 4*(lane-32);
  const bf16* heb = he + (size_t)b * Ll * 256;
  bf16* hiob = hio + (size_t)b * Ll * 256;
  float bias0 = isIn ? cbiah[c]   : cboah[c-128];
  float bias1 = isIn ? cbiah[c+1] : cboah[c-127];
  float bias2 = isIn ? cbiah[c+2] : cboah[c-126];
  float bias3 = isIn ? cbiah[c+3] : cboah[c-125];
#pragma unroll
  for (int s = 0; s < 2; s++) {
    int i = chunk*8 + wave + 4*s;
    const unsigned* mrow = (isIn ? adjT_g : adj_g) + ((size_t)b*Ll + i) * 8;
    float a0=0.f, a1=0.f, a2=0.f, a3=0.f;
    for (int wd = 0; wd < 7; wd++) {
      unsigned bits = mrow[wd];
      while (bits) {
        int j = (wd << 5) + __builtin_ctz(bits); bits &= bits - 1;
        ushort4v h4 = *(const ushort4v*)(heb + (size_t)j*256 + c);
        a0 += us2f(h4.x); a1 += us2f(h4.y); a2 += us2f(h4.z); a3 += us2f(h4.w);
      }
    }
    float r = isIn ? rin_g[b*Ll + i] : rout_g[b*Ll + i];
    ushort4v o;
    o.x = f2us(bias0 + r*a0); o.y = f2us(bias1 + r*a1);
    o.z = f2us(bias2 + r*a2); o.w = f2us(bias3 + r*a3);
    *(ushort4v*)(hiob + (size_t)i*256 + c) = o;
  }
}

// ---------------------------------------------------------------- KV+ATTN fused (v2): stride-266 kvL + phase-A prefetch
// LDS pool (163,488 <= 163,840): xs 56,576 | kvL 200xKVS shorts 106,400 | htL 512.
struct KAP {
  const bf16 *gi, *gh; const void* emb; const int* seqs; const int* alias_g; const int* lens;
  const bf16 *cPos, *cWkv; const float* bias_kv;
  const bf16 *cWq, *cWo, *cW1, *cW2;
  const float *cbq, *cbo, *cb1, *cb2, *cln;
  void* out;
};
__device__ __forceinline__ float dot128i(const bf16* __restrict__ wrow, const float* __restrict__ vin) {
  const short8* wr = (const short8*)wrow;
  float a0=0.f, a1=0.f, a2=0.f, a3=0.f;
#pragma unroll
  for (int kk = 0; kk < 4; kk++) {
    short8 w0 = wr[kk*4+0], w1 = wr[kk*4+1], w2 = wr[kk*4+2], w3 = wr[kk*4+3];
#pragma unroll
    for (int j = 0; j < 8; j++) {
      a0 += vin[kk*32 +      j] * us2f((unsigned short)w0[j]);
      a1 += vin[kk*32 + 8  + j] * us2f((unsigned short)w1[j]);
      a2 += vin[kk*32 + 16 + j] * us2f((unsigned short)w2[j]);
      a3 += vin[kk*32 + 24 + j] * us2f((unsigned short)w3[j]);
    }
  }
  return (a0+a1)+(a2+a3);
}
__device__ __forceinline__ float wave_sum(float v) {
#pragma unroll
  for (int m = 1; m < 64; m <<= 1) v += __shfl_xor(v, m, 64);
  return v;
}
__device__ __forceinline__ float wave_max(float v) {
#pragma unroll
  for (int m = 1; m < 64; m <<= 1) v = fmaxf(v, __shfl_xor(v, m, 64));
  return v;
}
// GRU elementwise on 8-wide bf16 fragments; writes xs row and (if last) htL
__device__ __forceinline__ void gru8(short8 vir, short8 vii, short8 vnn,
                                     short8 whr, short8 whi, short8 whn,
                                     short8 hv, short8 pv, bool isLast,
                                     short* xrow, float* htL, int jv)
{
  short8 o;
#pragma unroll
  for (int e = 0; e < 8; e++) {
    float ir = us2f((unsigned short)vir[e]), ii = us2f((unsigned short)vii[e]), inn = us2f((unsigned short)vnn[e]);
    float hr = us2f((unsigned short)whr[e]), hi = us2f((unsigned short)whi[e]), hn = us2f((unsigned short)whn[e]);
    float r  = 1.f / (1.f + __expf(-(ir + hr)));
    float z  = 1.f / (1.f + __expf(-(ii + hi)));
    float arg = inn + r * hn;
    float ex = __expf(-2.f * arg);
    float ng = (1.f - ex) / (1.f + ex);
    float h  = us2f((unsigned short)hv[e]);
    float sh = ng + z * (h - ng);
    o[e] = (short)f2us(sh + us2f((unsigned short)pv[e]));
    if (isLast) htL[jv*8 + e] = sh;
  }
  *(short8*)xrow = o;
}
__global__ __launch_bounds__(256) void kv_attn(KAP p)
{
  __shared__ __align__(16) char pool[163488];
  short* xs   = (short*)pool;                      // 208*136 shorts (dead after phase B)
  short* kvL  = (short*)(pool + 56576);            // 200 rows x KVS elems
  float* htL  = (float*)(pool + 56576 + 106400);   // 128 floats
  int* aliasL = (int*)(pool + 56576);              // overlay: dead before phase B writes
  int* seqL   = aliasL + 200;
  // k7-part scratch overlays xs (valid after post-phase-B barrier)
  float* qin  = (float*)pool;
  float* qv   = qin + 128;
  float* aout = qv + 128;
  float* hh   = aout + 128;
  float* f1   = hh + 128;
  float* pb0  = f1 + 128;                          // 256
  float* pb1  = pb0 + 256;                         // 256
  floatx4* av4 = (floatx4*)(pb1 + 256);            // 8*32 floatx4 (offset 4608, 16B aligned)
  float* sred = (float*)(av4 + 8*32);              // 8

  int b = blockIdx.x, t = threadIdx.x;
  int wave = t >> 6, lane = t & 63, q = lane >> 4, mr = lane & 15;
  int li = p.lens[b] - 1;
  int f32 = detect_f32((const unsigned short*)p.emb);
  if (t < Ll) { aliasL[t] = p.alias_g[b*Ll + t]; seqL[t] = p.seqs[b*Ll + t]; }
  for (int u = t; u < 8*136; u += 256) xs[Ll*136 + u] = 0;   // zero pad rows 200..207
  __syncthreads();
  // ---- phase A (unroll-2 prefetch): xs[tpos] = GRU(gates@alias, h=emb[seq]) + pos; ht -> htL
  const bf16* gib = p.gi + (size_t)b*Ll*384;
  const bf16* ghb = p.gh + (size_t)b*Ll*384;
  for (int u = t; u < Ll*16; u += 512) {
    int tposA = u >> 4, jvA = u & 15;
    int aA = aliasL[tposA], itA = seqL[tposA];
    const short8* ginA = (const short8*)(gib + (size_t)aA * 384);
    const short8* ghnA = (const short8*)(ghb + (size_t)aA * 384);
    short8 virA = ginA[jvA], viiA = ginA[16+jvA], vnnA = ginA[32+jvA];
    short8 whrA = ghnA[jvA], whiA = ghnA[16+jvA], whnA = ghnA[32+jvA];
    short8 hvA  = emb_chunk8(p.emb, itA, jvA, f32);
    short8 pvA  = ((const short8*)(p.cPos + tposA * Dd))[jvA];
    int uB = u + 256;
    bool hasB = (uB < Ll*16);                       // wave-uniform (t<128 last iter only)
    short8 virB, viiB, vnnB, whrB, whiB, whnB, hvB, pvB;
    int tposB = 0, jvB = 0;
    if (hasB) {
      tposB = uB >> 4; jvB = uB & 15;
      int aB = aliasL[tposB], itB = seqL[tposB];
      const short8* ginB = (const short8*)(gib + (size_t)aB * 384);
      const short8* ghnB = (const short8*)(ghb + (size_t)aB * 384);
      virB = ginB[jvB]; viiB = ginB[16+jvB]; vnnB = ginB[32+jvB];
      whrB = ghnB[jvB]; whiB = ghnB[16+jvB]; whnB = ghnB[32+jvB];
      hvB  = emb_chunk8(p.emb, itB, jvB, f32);
      pvB  = ((const short8*)(p.cPos + tposB * Dd))[jvB];
    }
    gru8(virA, viiA, vnnA, whrA, whiA, whnA, hvA, pvA, tposA == li, &xs[tposA*136 + jvA*8], htL, jvA);
    if (hasB)
      gru8(virB, viiB, vnnB, whrB, whiB, whnB, hvB, pvB, tposB == li, &xs[tposB*136 + jvB*8], htL, jvB);
  }
  __syncthreads();                                 // aliasL/seqL dead from here
  // ---- phase B: kvL = xs @ Wkv^T + bias (per-wave n-quadrant), written to LDS
  {
    short8 wf[4][4];
#pragma unroll
    for (int kk = 0; kk < 4; kk++)
#pragma unroll
      for (int j = 0; j < 4; j++) {
        int n = wave*64 + j*16 + mr;
        wf[kk][j] = *(const short8*)(p.cWkv + (size_t)n*128 + kk*32 + q*8);
      }
    for (int mt = 0; mt < 13; mt++) {
      short8 af[4];
#pragma unroll
      for (int kk = 0; kk < 4; kk++)
        af[kk] = *(const short8*)&xs[(mt*16 + mr)*136 + (kk*4+q)*8];
      floatx4 acc[4] = {};
#pragma unroll
      for (int kk = 0; kk < 4; kk++)
#pragma unroll
        for (int j = 0; j < 4; j++)
          acc[j] = __builtin_amdgcn_mfma_f32_16x16x32_bf16(wf[kk][j], af[kk], acc[j], 0, 0, 0);
      int m = mt*16 + mr;
      if (m < Ll) {
#pragma unroll
        for (int j = 0; j < 4; j++) {
          int n = wave*64 + j*16 + q*4;
          floatx4 bs = *(const floatx4*)(p.bias_kv + n);
          ushort4v o;
#pragma unroll
          for (int e = 0; e < 4; e++) o[e] = f2us(acc[j][e] + bs[e]);
          *(ushort4v*)&kvL[m*KVS + n] = o;
        }
      }
    }
  }
  __syncthreads();                                 // xs dead from here; kvL ready
  // ---- attention tail: x[li] = htL + pos[li]
  int c = t, w = wave, ln = lane;
  float xv = (c < 128) ? (htL[c] + b2f(p.cPos[li*Dd + c])) : 0.f;
  float s = wave_sum(xv), s2 = wave_sum(xv*xv);
  if (ln == 0) { sred[w] = s; sred[4+w] = s2; }
  __syncthreads();
  float mu = (sred[0]+sred[1]+sred[2]+sred[3]) * (1.f/128.f);
  float ms = (sred[4]+sred[5]+sred[6]+sred[7]) * (1.f/128.f);
  float rs = rsqrtf(fmaxf(ms - mu*mu, 0.f) + 1e-5f);
  __syncthreads();
  if (c < 128) qin[c] = (xv - mu) * rs * p.cln[c] + p.cln[128+c];
  __syncthreads();
  if (c < 128) qv[c] = p.cbq[c] + dot128i(p.cWq + c*128, qin);
  __syncthreads();
  float s0 = -3.0e38f, s1 = -3.0e38f;
  if (t <= li) {
    const short8* kr = (const short8*)&kvL[t*KVS];
    float a00=0.f,a01=0.f,a10=0.f,a11=0.f;
#pragma unroll
    for (int kk = 0; kk < 4; kk++) {
      short8 k0 = kr[kk*2], k1 = kr[kk*2+1], k2 = kr[8+kk*2], k3 = kr[8+kk*2+1];
#pragma unroll
      for (int j = 0; j < 8; j++) {
        a00 += qv[kk*16 + j]      * us2f((unsigned short)k0[j]);
        a01 += qv[kk*16 + 8 + j]  * us2f((unsigned short)k1[j]);
        a10 += qv[64 + kk*16 + j]     * us2f((unsigned short)k2[j]);
        a11 += qv[64 + kk*16 + 8 + j] * us2f((unsigned short)k3[j]);
      }
    }
    s0 = (a00+a01) * 0.125f; s1 = (a10+a11) * 0.125f;
  }
  float m0 = wave_max(s0), m1 = wave_max(s1);
  if (ln == 0) { sred[w] = m0; sred[4+w] = m1; }
  __syncthreads();
  m0 = fmaxf(fmaxf(sred[0],sred[1]), fmaxf(sred[2],sred[3]));
  m1 = fmaxf(fmaxf(sred[4],sred[5]), fmaxf(sred[6],sred[7]));
  __syncthreads();
  float e0 = (t <= li) ? __expf(s0 - m0) : 0.f;
  float e1 = (t <= li) ? __expf(s1 - m1) : 0.f;
  pb0[t] = e0; pb1[t] = e1;
  float l0 = wave_sum(e0), l1 = wave_sum(e1);
  if (ln == 0) { sred[w] = l0; sred[4+w] = l1; }
  __syncthreads();
  l0 = sred[0]+sred[1]+sred[2]+sred[3];
  l1 = sred[4]+sred[5]+sred[6]+sred[7];
  {
    int part = t >> 5, cq = t & 31, ch = cq * 4;
    int cnt = li + 1, cpp = (cnt + 7) >> 3;
    int j0 = part * cpp, j1 = min(j0 + cpp, cnt);
    const float* pbh = (ch < 64) ? pb0 : pb1;
    float a0=0.f,a1=0.f,a2=0.f,a3=0.f;
#pragma unroll 4
    for (int j = j0; j < j1; j++) {
      ushort4v v4 = *(const ushort4v*)&kvL[j*KVS + 128 + ch];
      float pw = pbh[j];
      a0 += pw*us2f(v4.x); a1 += pw*us2f(v4.y); a2 += pw*us2f(v4.z); a3 += pw*us2f(v4.w);
    }
    floatx4 o = {a0,a1,a2,a3};
    av4[part*32 + cq] = o;
  }
  __syncthreads();
  if (c < 128) {
    float l = (c < 64) ? l0 : l1;
    float acc = 0.f;
#pragma unroll
    for (int pp = 0; pp < 8; pp++) acc += ((const float*)&av4[pp*32 + (c>>2)])[c&3];
    aout[c] = acc / l;
  }
  __syncthreads();
  float x2v = 0.f;
  if (c < 128) x2v = qin[c] + p.cbo[c] + dot128i(p.cWo + c*128, aout);
  s = wave_sum((c<128)?x2v:0.f); s2 = wave_sum((c<128)?x2v*x2v:0.f);
  if (ln == 0) { sred[w] = s; sred[4+w] = s2; }
  __syncthreads();
  mu = (sred[0]+sred[1]+sred[2]+sred[3]) * (1.f/128.f);
  ms = (sred[4]+sred[5]+sred[6]+sred[7]) * (1.f/128.f);
  rs = rsqrtf(fmaxf(ms - mu*mu, 0.f) + 1e-5f);
  __syncthreads();
  if (c < 128) hh[c] = (x2v - mu) * rs * p.cln[256+c] + p.cln[384+c];
  __syncthreads();
  if (c < 128) f1[c] = fmaxf(p.cb1[c] + dot128i(p.cW1 + c*128, hh), 0.f);
  __syncthreads();
  float x3v = 0.f;
  if (c < 128) x3v = hh[c] + p.cb2[c] + dot128i(p.cW2 + c*128, f1);
  s = wave_sum((c<128)?x3v:0.f); s2 = wave_sum((c<128)?x3v*x3v:0.f);
  if (ln == 0) { sred[w] = s; sred[4+w] = s2; }
  __syncthreads();
  mu = (sred[0]+sred[1]+sred[2]+sred[3]) * (1.f/128.f);
  ms = (sred[4]+sred[5]+sred[6]+sred[7]) * (1.f/128.f);
  rs = rsqrtf(fmaxf(ms - mu*mu, 0.f) + 1e-5f);
  if (c < 128) {
    float lf = (x3v - mu) * rs * p.cln[512+c] + p.cln[640+c];
    float outv = 0.6f * lf + 0.4f * htL[c];
    if (f32) ((float*)p.out)[b*Dd + c] = outv;
    else     ((bf16*)p.out)[b*Dd + c]  = f2b(outv);
  }
}

// ---------------------------------------------------------------- host
extern "C" void kernel_launch(void* const* d_in, const int* in_sizes, int n_in,
                              void* d_out, int out_size, void* d_ws, size_t ws_size,
                              hipStream_t stream)
{
  (void)in_sizes; (void)n_in; (void)out_size; (void)ws_size;
  const void* item_emb = d_in[0];
  const int* seqs = (const int*)d_in[30];
  const int* lens = (const int*)d_in[31];

  char* wsp = (char*)d_ws;
  size_t o = 0;
  auto alloc = [&](size_t sz) { void* p = wsp + o; o += (sz + 255) & ~(size_t)255; return p; };
  int*      alias_g = (int*)alloc((size_t)BL*4);
  int*      items_g = (int*)alloc((size_t)BL*4);
  float*    rin_g   = (float*)alloc((size_t)BL*4);
  float*    rout_g  = (float*)alloc((size_t)BL*4);
  unsigned* adj_g   = (unsigned*)alloc((size_t)BL*8*4);
  unsigned* adjT_g  = (unsigned*)alloc((size_t)BL*8*4);
  // cWhe and cWhh MUST be adjacent (merged he+gh dispatch reads 640 rows from cWhe).
  bf16*     cWhe    = (bf16*)alloc(32768*2);     // 65536 B, 256-aligned
  bf16*     cWhh    = (bf16*)alloc(49152*2);
  bf16*     cWih    = (bf16*)alloc(98304*2);
  bf16*     cWkv    = (bf16*)alloc(32768*2);
  bf16*     cWq     = (bf16*)alloc(16384*2);
  bf16*     cWo     = (bf16*)alloc(16384*2);
  bf16*     cW1     = (bf16*)alloc(16384*2);
  bf16*     cW2     = (bf16*)alloc(16384*2);
  bf16*     cPos    = (bf16*)alloc(25600*2);
  // bias_he and bias_gh MUST be adjacent (merged bias[640]).
  float*    bias_he = (float*)alloc(256*4);      // 1024 B
  float*    bias_gh = (float*)alloc(384*4);
  float*    bias_gi = (float*)alloc(384*4);
  float*    bias_kv = (float*)alloc(256*4);
  float*    cbq     = (float*)alloc(128*4);
  float*    cbo     = (float*)alloc(128*4);
  float*    cb1     = (float*)alloc(128*4);
  float*    cb2     = (float*)alloc(128*4);
  float*    cbiah   = (float*)alloc(128*4);
  float*    cboah   = (float*)alloc(128*4);
  float*    cln     = (float*)alloc(768*4);
  bf16*     he      = (bf16*)alloc((size_t)BL*256*2);
  bf16*     hio     = (bf16*)alloc((size_t)BL*256*2);
  bf16*     gi      = (bf16*)alloc((size_t)BL*384*2);
  bf16*     gh      = (bf16*)alloc((size_t)BL*384*2);

  PackP pp = { d_in[2], d_in[4], d_in[8], d_in[10], d_in[16], d_in[18], d_in[14], d_in[20],
               d_in[24], d_in[26], d_in[1],
               d_in[3], d_in[5], d_in[9], d_in[11], d_in[17], d_in[19], d_in[15], d_in[21],
               d_in[25], d_in[27], d_in[6], d_in[7],
               d_in[12], d_in[13], d_in[22], d_in[23], d_in[28], d_in[29],
               cWhe, cWih, cWhh, cWkv, cWq, cWo, cW1, cW2, cPos,
               bias_he, bias_gi, bias_gh, bias_kv, cbq, cbo, cb1, cb2, cbiah, cboah, cln,
               seqs, alias_g, items_g, rin_g, rout_g, adj_g, adjT_g };
  k01<<<Bb + 1199, 256, 0, stream>>>(pp);
  // G1: he (N=256) + gh (N=384), A gathered ONCE per m-block, 5 n-tiles in-kernel
  gemm_he2<<<BL/128, 256, 0, stream>>>(item_emb, items_g, cWhe, bias_he, he, 256, gh, 384, 256);
  k3_agg<<<Bb*25, 256, 0, stream>>>(he, adj_g, adjT_g, rin_g, rout_g, cbiah, cboah, hio);
  // G2: gi (K=256, N=384)
  gemm6<256><<<dim3(BL/128, 3), 256, 0, stream>>>(hio, cWih, bias_gi, gi, 384, gi, 384, 1<<30);
  // KV+ATTN fused: GRU + gather + pos + kv-GEMM (LDS-resident) + attention tail per batch
  KAP kp = { gi, gh, item_emb, seqs, alias_g, lens, cPos, cWkv, bias_kv,
             cWq, cWo, cW1, cW2, cbq, cbo, cb1, cb2, cln, d_out };
  kv_attn<<<Bb, 256, 0, stream>>>(kp);
}

// Round 15
// 270.728 us; speedup vs baseline: 1.0012x; 1.0012x over previous
//
#include <hip/hip_runtime.h>
#include <hip/hip_bf16.h>

#define Bb 256
#define Ll 200
#define Dd 128
#define BL (Bb*Ll)
#define KVS 266   // kvL row stride in shorts: 133 dwords (odd) -> conflict-free row-indexed b128 reads

typedef __hip_bfloat16 bf16;
typedef __attribute__((ext_vector_type(8))) short short8;
typedef __attribute__((ext_vector_type(4))) unsigned short ushort4v;
typedef __attribute__((ext_vector_type(4))) float floatx4;

__device__ __forceinline__ float b2f(bf16 v) { return __bfloat162float(v); }
__device__ __forceinline__ bf16  f2b(float v) { return __float2bfloat16(v); }
__device__ __forceinline__ float us2f(unsigned short u) { return __uint_as_float(((unsigned)u) << 16); }
__device__ __forceinline__ unsigned short f2us(float v) { bf16 t = f2b(v); return *(unsigned short*)&t; }
__device__ __forceinline__ float ldf(const void* p, int i, int f32) {
  return f32 ? ((const float*)p)[i] : b2f(((const bf16*)p)[i]);
}
// dtype probe: uniform(-.088,.088) bf16 never has exp>=0x7F; f32 mantissa halves do ~50%.
__device__ __forceinline__ int detect_f32(const unsigned short* __restrict__ w) {
  unsigned short u = w[threadIdx.x & 63];
  return (__ballot(((u >> 7) & 0xFF) >= 0x7F) != 0ull) ? 1 : 0;
}
// async global->LDS DMA, 16B per lane; LDS dest = wave-uniform base + lane*16
__device__ __forceinline__ void load_lds16(const void* g, void* l) {
  __builtin_amdgcn_global_load_lds((const __attribute__((address_space(1))) unsigned int*)g,
                                   (__attribute__((address_space(3))) unsigned int*)l, 16, 0, 0);
}
// gather one 8-elem chunk (cols 8g..8g+7) of emb row `it`, dtype-aware, as bf16x8 (vectorized)
__device__ __forceinline__ short8 emb_chunk8(const void* __restrict__ emb, int it, int g, int f32) {
  short8 o;
  if (f32) {
    const float4* e = (const float4*)((const float*)emb + (size_t)it * 128 + g * 8);
    float4 a = e[0], b = e[1];
    o[0] = (short)f2us(a.x); o[1] = (short)f2us(a.y); o[2] = (short)f2us(a.z); o[3] = (short)f2us(a.w);
    o[4] = (short)f2us(b.x); o[5] = (short)f2us(b.y); o[6] = (short)f2us(b.z); o[7] = (short)f2us(b.w);
  } else {
    o = ((const short8*)((const bf16*)emb + (size_t)it * 128))[g];
  }
  return o;
}

// ---------------------------------------------------------------- K01: graph build (blocks 0..255) + pack (rest)
struct PackP {
  const void *W_ei,*W_eo,*w_ih,*w_hh,*Wk,*Wv,*Wqp,*Wop,*W1p,*W2p,*pos;
  const void *b_ei,*b_eo,*b_ih,*b_hh,*bk,*bv,*bqp,*bop,*b1p,*b2p,*biah,*boah;
  const void *ln1g,*ln1b,*ln2g,*ln2b,*lnfg,*lnfb;
  bf16 *cWhe,*cWih,*cWhh,*cWkv,*cWq,*cWo,*cW1,*cW2,*cPos;
  float *bias_he,*bias_gi,*bias_gh,*bias_kv,*cbq,*cbo,*cb1,*cb2,*cbiah,*cboah,*cln;
  const int* seqs;
  int *alias_g, *items_g; float *rin_g, *rout_g; unsigned *adj_g, *adjT_g;
};
__global__ __launch_bounds__(256) void k01(PackP p) {
  __shared__ alignas(16) int s[Ll];
  __shared__ int al[Ll], its[Ll];
  __shared__ alignas(4) unsigned char isf[Ll];
  __shared__ unsigned adjL[Ll*8], adjTL[Ll*8];
  if (blockIdx.x >= Bb) {
    int idx = (blockIdx.x - Bb) * 256 + threadIdx.x;       // < 306944
    int f32 = detect_f32((const unsigned short*)p.W_ei);
    if (idx < 131072) {
      if (idx < 32768) {
        int r = idx >> 7, c = idx & 127;
        p.cWhe[idx] = f2b(r < 128 ? ldf(p.W_ei, r*128+c, f32) : ldf(p.W_eo, (r-128)*128+c, f32));
      } else p.cWih[idx-32768] = f2b(ldf(p.w_ih, idx-32768, f32));
    } else if (idx < 278528) {
      if (idx < 180224)      p.cWhh[idx-131072] = f2b(ldf(p.w_hh, idx-131072, f32));
      else if (idx < 212992) {
        int i = idx - 180224; int r = i >> 7, c = i & 127;
        p.cWkv[i] = f2b(r < 128 ? ldf(p.Wk, r*128+c, f32) : ldf(p.Wv, (r-128)*128+c, f32));
      }
      else if (idx < 229376) p.cWq[idx-212992] = f2b(ldf(p.Wqp, idx-212992, f32));
      else if (idx < 245760) p.cWo[idx-229376] = f2b(ldf(p.Wop, idx-229376, f32));
      else if (idx < 262144) p.cW1[idx-245760] = f2b(ldf(p.W1p, idx-245760, f32));
      else                   p.cW2[idx-262144] = f2b(ldf(p.W2p, idx-262144, f32));
    } else if (idx < 304128) {
      p.cPos[idx-278528] = f2b(ldf(p.pos, idx-278528, f32));
    } else {
      int j = idx - 304128;                          // < 2816
      if      (j < 256)  p.bias_he[j]     = (j<128) ? ldf(p.b_ei,j,f32) : ldf(p.b_eo,j-128,f32);
      else if (j < 640)  p.bias_gi[j-256] = ldf(p.b_ih, j-256, f32);
      else if (j < 1024) p.bias_gh[j-640] = ldf(p.b_hh, j-640, f32);
      else if (j < 1280) { int c=j-1024; p.bias_kv[c] = (c<128)? ldf(p.bk,c,f32): ldf(p.bv,c-128,f32); }
      else if (j < 1408) p.cbq[j-1280]   = ldf(p.bqp, j-1280, f32);
      else if (j < 1536) p.cbo[j-1408]   = ldf(p.bop, j-1408, f32);
      else if (j < 1664) p.cb1[j-1536]   = ldf(p.b1p, j-1536, f32);
      else if (j < 1792) p.cb2[j-1664]   = ldf(p.b2p, j-1664, f32);
      else if (j < 1920) p.cbiah[j-1792] = ldf(p.biah, j-1792, f32);
      else if (j < 2048) p.cboah[j-1920] = ldf(p.boah, j-1920, f32);
      else {
        int i = j - 2048, g = i >> 7, c2 = i & 127;
        const void* s6 = g==0?p.ln1g: g==1?p.ln1b: g==2?p.ln2g: g==3?p.ln2b: g==4?p.lnfg: p.lnfb;
        p.cln[i] = ldf(s6, c2, f32);
      }
    }
    return;
  }
  // ---- graph part (one block per batch row), int4-vectorized inner loops
  int b = blockIdx.x, t = threadIdx.x;
  if (t < Ll) s[t] = p.seqs[b*Ll + t];
  for (int i = t; i < Ll*8; i += 256) { adjL[i] = 0u; adjTL[i] = 0u; }
  __syncthreads();
  const int4* s4 = (const int4*)s;
  if (t < Ll) {
    int v = s[t]; int dup = 0;
    int nb = t >> 2;
    for (int j4 = 0; j4 < nb; j4++) {
      int4 sv = s4[j4];
      dup |= (sv.x==v) | (sv.y==v) | (sv.z==v) | (sv.w==v);
    }
    for (int j = nb*4; j < t; j++) dup |= (s[j]==v);
    isf[t] = dup ? 0 : 1; its[t] = 0;
  }
  __syncthreads();
  const unsigned* isfw = (const unsigned*)isf;
  if (t < Ll) {
    int v = s[t], r = 0;
    for (int j4 = 0; j4 < Ll/4; j4++) {
      int4 sv = s4[j4];
      unsigned fw = isfw[j4];
      r += ((fw & 0xffu)       && sv.x < v);
      r += ((fw & 0xff00u)     && sv.y < v);
      r += ((fw & 0xff0000u)   && sv.z < v);
      r += ((fw & 0xff000000u) && sv.w < v);
    }
    al[t] = r;
  }
  __syncthreads();
  if (t < Ll && isf[t]) its[al[t]] = s[t];
  if (t < Ll-1 && s[t+1] > 0) {
    int u = al[t], v = al[t+1];
    atomicOr(&adjL [u*8 + (v >> 5)], 1u << (v & 31));
    atomicOr(&adjTL[v*8 + (u >> 5)], 1u << (u & 31));
  }
  __syncthreads();
  if (t < Ll) {
    int od = 0, id = 0;
    for (int wd = 0; wd < 7; wd++) { od += __popc(adjL[t*8+wd]); id += __popc(adjTL[t*8+wd]); }
    p.rout_g [b*Ll + t] = 1.0f / (float)max(od, 1);
    p.rin_g  [b*Ll + t] = 1.0f / (float)max(id, 1);
    p.alias_g[b*Ll + t] = al[t];
    p.items_g[b*Ll + t] = its[t];
  }
  for (int i = t; i < Ll*8; i += 256) { p.adj_g[b*Ll*8 + i] = adjL[i]; p.adjT_g[b*Ll*8 + i] = adjTL[i]; }
}

// ---------------------------------------------------------------- GEMM-HE v2: A gathered ONCE, loop over 5 n-tiles
__global__ __launch_bounds__(256) void gemm_he2(const void* __restrict__ emb, const int* __restrict__ items_g,
    const bf16* __restrict__ W, const float* __restrict__ bias,
    bf16* __restrict__ out_lo, int Nlo, bf16* __restrict__ out_hi, int Nhi, int split)
{
  __shared__ short As[128*128];                 // 32 KB
  __shared__ short Ws[128*128];                 // 32 KB
  int t = threadIdx.x;
  int wave = t >> 6, lane = t & 63;
  int q = lane >> 4, mr = lane & 15;
  int wm = wave & 1, wn = wave >> 1;
  int m0 = blockIdx.x * 128;
  int f32 = detect_f32((const unsigned short*)emb);
  {
    int r = t >> 1, half = t & 1;
    int it = items_g[m0 + r];
#pragma unroll
    for (int g8 = 0; g8 < 8; g8++) {
      int g = half*8 + g8;
      short8 o = emb_chunk8(emb, it, g, f32);
      *(short8*)&As[r*128 + (g ^ (r & 15))*8] = o;
    }
  }
  int srow = lane >> 4, c16 = lane & 15;
  for (int nt = 0; nt < 5; nt++) {
    int n0 = nt * 128;
#pragma unroll
    for (int i = 0; i < 8; i++) {
      int seg = wave*8 + i;
      int r = seg*4 + srow;
      int gch = c16 ^ (r & 15);
      load_lds16(W + (size_t)(n0 + r) * 128 + gch*8, &Ws[seg*512]);
    }
    __syncthreads();
    floatx4 acc[4][4] = {};
#pragma unroll
    for (int kk = 0; kk < 4; kk++) {
      short8 af[4], wf[4];
#pragma unroll
      for (int i = 0; i < 4; i++) {
        int row = wm*64 + i*16 + mr;
        af[i] = *(const short8*)(&As[row*128 + ((kk*4+q) ^ (row&15))*8]);
      }
#pragma unroll
      for (int j = 0; j < 4; j++) {
        int row = wn*64 + j*16 + mr;
        wf[j] = *(const short8*)(&Ws[row*128 + ((kk*4+q) ^ (row&15))*8]);
      }
#pragma unroll
      for (int i = 0; i < 4; i++)
#pragma unroll
        for (int j = 0; j < 4; j++)
          acc[i][j] = __builtin_amdgcn_mfma_f32_16x16x32_bf16(wf[j], af[i], acc[i][j], 0, 0, 0);
    }
#pragma unroll
    for (int j = 0; j < 4; j++) {
      int ng = n0 + wn*64 + j*16 + q*4;
      floatx4 bs = *(const floatx4*)(bias + ng);
      bf16* outp; int col, stride;
      if (ng < split) { outp = out_lo; col = ng; stride = Nlo; }
      else            { outp = out_hi; col = ng - split; stride = Nhi; }
#pragma unroll
      for (int i = 0; i < 4; i++) {
        int m = m0 + wm*64 + i*16 + mr;
        ushort4v o;
#pragma unroll
        for (int e = 0; e < 4; e++) o[e] = f2us(acc[i][j][e] + bs[e]);
        *(ushort4v*)(outp + (size_t)m * stride + col) = o;
      }
    }
    if (nt + 1 < 5) __syncthreads();
  }
}

// ---------------------------------------------------------------- MFMA GEMM v6 (used for gi: K=256)
template<int K>
__global__ __launch_bounds__(256) void gemm6(const bf16* __restrict__ A, const bf16* __restrict__ W,
    const float* __restrict__ bias,
    bf16* __restrict__ out_lo, int Nlo, bf16* __restrict__ out_hi, int Nhi, int split)
{
  __shared__ short As[128*128];                 // 32 KB
  __shared__ short Ws[128*128];                 // 32 KB
  int t = threadIdx.x;
  int wave = t >> 6, lane = t & 63;
  int q = lane >> 4, mr = lane & 15;
  int wm = wave & 1, wn = wave >> 1;
  int m0 = blockIdx.x * 128, n0 = blockIdx.y * 128;
  int srow = lane >> 4;
  int c16 = lane & 15;
  floatx4 acc[4][4] = {};
  for (int k0 = 0; k0 < K; k0 += 128) {
#pragma unroll
    for (int i = 0; i < 8; i++) {
      int seg = wave*8 + i;
      int r = seg*4 + srow;
      int gch = c16 ^ (r & 15);
      load_lds16(A + (size_t)(m0 + r) * K + k0 + gch*8, &As[seg*512]);
      load_lds16(W + (size_t)(n0 + r) * K + k0 + gch*8, &Ws[seg*512]);
    }
    __syncthreads();
#pragma unroll
    for (int kk = 0; kk < 4; kk++) {
      short8 af[4], wf[4];
#pragma unroll
      for (int i = 0; i < 4; i++) {
        int row = wm*64 + i*16 + mr;
        af[i] = *(const short8*)(&As[row*128 + ((kk*4+q) ^ (row&15))*8]);
      }
#pragma unroll
      for (int j = 0; j < 4; j++) {
        int row = wn*64 + j*16 + mr;
        wf[j] = *(const short8*)(&Ws[row*128 + ((kk*4+q) ^ (row&15))*8]);
      }
#pragma unroll
      for (int i = 0; i < 4; i++)
#pragma unroll
        for (int j = 0; j < 4; j++)
          acc[i][j] = __builtin_amdgcn_mfma_f32_16x16x32_bf16(wf[j], af[i], acc[i][j], 0, 0, 0);
    }
    if (k0 + 128 < K) __syncthreads();
  }
#pragma unroll
  for (int j = 0; j < 4; j++) {
    int ng = n0 + wn*64 + j*16 + q*4;
    floatx4 bs = *(const floatx4*)(bias + ng);
    bf16* outp; int col, stride;
    if (ng < split) { outp = out_lo; col = ng; stride = Nlo; }
    else            { outp = out_hi; col = ng - split; stride = Nhi; }
#pragma unroll
    for (int i = 0; i < 4; i++) {
      int m = m0 + wm*64 + i*16 + mr;
      ushort4v o;
#pragma unroll
      for (int e = 0; e < 4; e++) o[e] = f2us(acc[i][j][e] + bs[e]);
      *(ushort4v*)(outp + (size_t)m * stride + col) = o;
    }
  }
}

// ---------------------------------------------------------------- K3: sparse graph aggregation (one wave per node)
__global__ __launch_bounds__(256) void k3_agg(const bf16* __restrict__ he,
    const unsigned* __restrict__ adj_g, const unsigned* __restrict__ adjT_g,
    const float* __restrict__ rin_g, const float* __restrict__ rout_g,
    const float* __restrict__ cbiah, const float* __restrict__ cboah, bf16* __restrict__ hio)
{
  int b = blockIdx.x / 25, chunk = blockIdx.x % 25;
  int wave = threadIdx.x >> 6, lane = threadIdx.x & 63;
  bool isIn = lane < 32;
  int c = isIn ? 4*lane : 128 + 4*(lane-32);
  const bf16* heb = he + (size_t)b * Ll * 256;
  bf16* hiob = hio + (size_t)b * Ll * 256;
  float bias0 = isIn ? cbiah[c]   : cboah[c-128];
  float bias1 = isIn ? cbiah[c+1] : cboah[c-127];
  float bias2 = isIn ? cbiah[c+2] : cboah[c-126];
  float bias3 = isIn ? cbiah[c+3] : cboah[c-125];
#pragma unroll
  for (int s = 0; s < 2; s++) {
    int i = chunk*8 + wave + 4*s;
    const unsigned* mrow = (isIn ? adjT_g : adj_g) + ((size_t)b*Ll + i) * 8;
    float a0=0.f, a1=0.f, a2=0.f, a3=0.f;
    for (int wd = 0; wd < 7; wd++) {
      unsigned bits = mrow[wd];
      while (bits) {
        int j = (wd << 5) + __builtin_ctz(bits); bits &= bits - 1;
        ushort4v h4 = *(const ushort4v*)(heb + (size_t)j*256 + c);
        a0 += us2f(h4.x); a1 += us2f(h4.y); a2 += us2f(h4.z); a3 += us2f(h4.w);
      }
    }
    float r = isIn ? rin_g[b*Ll + i] : rout_g[b*Ll + i];
    ushort4v o;
    o.x = f2us(bias0 + r*a0); o.y = f2us(bias1 + r*a1);
    o.z = f2us(bias2 + r*a2); o.w = f2us(bias3 + r*a3);
    *(ushort4v*)(hiob + (size_t)i*256 + c) = o;
  }
}

// ---------------------------------------------------------------- KV+ATTN fused (v3): round-13 simple phase A + stride-266 kvL
// LDS pool (163,488 <= 163,840): xs 56,576 | kvL 200xKVS shorts 106,400 | htL 512.
struct KAP {
  const bf16 *gi, *gh; const void* emb; const int* seqs; const int* alias_g; const int* lens;
  const bf16 *cPos, *cWkv; const float* bias_kv;
  const bf16 *cWq, *cWo, *cW1, *cW2;
  const float *cbq, *cbo, *cb1, *cb2, *cln;
  void* out;
};
__device__ __forceinline__ float dot128i(const bf16* __restrict__ wrow, const float* __restrict__ vin) {
  const short8* wr = (const short8*)wrow;
  float a0=0.f, a1=0.f, a2=0.f, a3=0.f;
#pragma unroll
  for (int kk = 0; kk < 4; kk++) {
    short8 w0 = wr[kk*4+0], w1 = wr[kk*4+1], w2 = wr[kk*4+2], w3 = wr[kk*4+3];
#pragma unroll
    for (int j = 0; j < 8; j++) {
      a0 += vin[kk*32 +      j] * us2f((unsigned short)w0[j]);
      a1 += vin[kk*32 + 8  + j] * us2f((unsigned short)w1[j]);
      a2 += vin[kk*32 + 16 + j] * us2f((unsigned short)w2[j]);
      a3 += vin[kk*32 + 24 + j] * us2f((unsigned short)w3[j]);
    }
  }
  return (a0+a1)+(a2+a3);
}
__device__ __forceinline__ float wave_sum(float v) {
#pragma unroll
  for (int m = 1; m < 64; m <<= 1) v += __shfl_xor(v, m, 64);
  return v;
}
__device__ __forceinline__ float wave_max(float v) {
#pragma unroll
  for (int m = 1; m < 64; m <<= 1) v = fmaxf(v, __shfl_xor(v, m, 64));
  return v;
}
__global__ __launch_bounds__(256) void kv_attn(KAP p)
{
  __shared__ __align__(16) char pool[163488];
  short* xs   = (short*)pool;                      // 208*136 shorts (dead after phase B)
  short* kvL  = (short*)(pool + 56576);            // 200 rows x KVS elems
  float* htL  = (float*)(pool + 56576 + 106400);   // 128 floats
  int* aliasL = (int*)(pool + 56576);              // overlay: dead before phase B writes
  int* seqL   = aliasL + 200;
  // k7-part scratch overlays xs (valid after post-phase-B barrier)
  float* qin  = (float*)pool;
  float* qv   = qin + 128;
  float* aout = qv + 128;
  float* hh   = aout + 128;
  float* f1   = hh + 128;
  float* pb0  = f1 + 128;                          // 256
  float* pb1  = pb0 + 256;                         // 256
  floatx4* av4 = (floatx4*)(pb1 + 256);            // 8*32 floatx4 (offset 4608, 16B aligned)
  float* sred = (float*)(av4 + 8*32);              // 8

  int b = blockIdx.x, t = threadIdx.x;
  int wave = t >> 6, lane = t & 63, q = lane >> 4, mr = lane & 15;
  int li = p.lens[b] - 1;
  int f32 = detect_f32((const unsigned short*)p.emb);
  if (t < Ll) { aliasL[t] = p.alias_g[b*Ll + t]; seqL[t] = p.seqs[b*Ll + t]; }
  for (int u = t; u < 8*136; u += 256) xs[Ll*136 + u] = 0;   // zero pad rows 200..207
  __syncthreads();
  // ---- phase A (simple loop — compiler schedules the 7 loads/iter fine):
  // xs[tpos] = GRU(gates at row alias[tpos], h = emb[seqs[tpos]]) + pos[tpos]; ht -> htL
  for (int u = t; u < Ll*16; u += 256) {
    int tpos = u >> 4, jv = u & 15;
    int a = aliasL[tpos];
    int it = seqL[tpos];
    const short8* gin = (const short8*)(p.gi + ((size_t)b*Ll + a) * 384);
    const short8* ghn = (const short8*)(p.gh + ((size_t)b*Ll + a) * 384);
    short8 vir = gin[jv], vii = gin[16+jv], vnn = gin[32+jv];
    short8 whr = ghn[jv], whi = ghn[16+jv], whn = ghn[32+jv];
    short8 hv  = emb_chunk8(p.emb, it, jv, f32);
    short8 pv  = ((const short8*)(p.cPos + tpos * Dd))[jv];
    bool isLast = (tpos == li);
    short8 o;
#pragma unroll
    for (int e = 0; e < 8; e++) {
      float ir = us2f((unsigned short)vir[e]), ii = us2f((unsigned short)vii[e]), inn = us2f((unsigned short)vnn[e]);
      float hr = us2f((unsigned short)whr[e]), hi = us2f((unsigned short)whi[e]), hn = us2f((unsigned short)whn[e]);
      float r  = 1.f / (1.f + __expf(-(ir + hr)));
      float z  = 1.f / (1.f + __expf(-(ii + hi)));
      float arg = inn + r * hn;
      float ex = __expf(-2.f * arg);
      float ng = (1.f - ex) / (1.f + ex);
      float h  = us2f((unsigned short)hv[e]);
      float sh = ng + z * (h - ng);
      o[e] = (short)f2us(sh + us2f((unsigned short)pv[e]));
      if (isLast) htL[jv*8 + e] = sh;
    }
    *(short8*)&xs[tpos*136 + jv*8] = o;
  }
  __syncthreads();                                 // aliasL/seqL dead from here
  // ---- phase B: kvL = xs @ Wkv^T + bias (per-wave n-quadrant), written to LDS
  {
    short8 wf[4][4];
#pragma unroll
    for (int kk = 0; kk < 4; kk++)
#pragma unroll
      for (int j = 0; j < 4; j++) {
        int n = wave*64 + j*16 + mr;
        wf[kk][j] = *(const short8*)(p.cWkv + (size_t)n*128 + kk*32 + q*8);
      }
    for (int mt = 0; mt < 13; mt++) {
      short8 af[4];
#pragma unroll
      for (int kk = 0; kk < 4; kk++)
        af[kk] = *(const short8*)&xs[(mt*16 + mr)*136 + (kk*4+q)*8];
      floatx4 acc[4] = {};
#pragma unroll
      for (int kk = 0; kk < 4; kk++)
#pragma unroll
        for (int j = 0; j < 4; j++)
          acc[j] = __builtin_amdgcn_mfma_f32_16x16x32_bf16(wf[kk][j], af[kk], acc[j], 0, 0, 0);
      int m = mt*16 + mr;
      if (m < Ll) {
#pragma unroll
        for (int j = 0; j < 4; j++) {
          int n = wave*64 + j*16 + q*4;
          floatx4 bs = *(const floatx4*)(p.bias_kv + n);
          ushort4v o;
#pragma unroll
          for (int e = 0; e < 4; e++) o[e] = f2us(acc[j][e] + bs[e]);
          *(ushort4v*)&kvL[m*KVS + n] = o;
        }
      }
    }
  }
  __syncthreads();                                 // xs dead from here; kvL ready
  // ---- attention tail: x[li] = htL + pos[li]
  int c = t, w = wave, ln = lane;
  float xv = (c < 128) ? (htL[c] + b2f(p.cPos[li*Dd + c])) : 0.f;
  float s = wave_sum(xv), s2 = wave_sum(xv*xv);
  if (ln == 0) { sred[w] = s; sred[4+w] = s2; }
  __syncthreads();
  float mu = (sred[0]+sred[1]+sred[2]+sred[3]) * (1.f/128.f);
  float ms = (sred[4]+sred[5]+sred[6]+sred[7]) * (1.f/128.f);
  float rs = rsqrtf(fmaxf(ms - mu*mu, 0.f) + 1e-5f);
  __syncthreads();
  if (c < 128) qin[c] = (xv - mu) * rs * p.cln[c] + p.cln[128+c];
  __syncthreads();
  if (c < 128) qv[c] = p.cbq[c] + dot128i(p.cWq + c*128, qin);
  __syncthreads();
  float s0 = -3.0e38f, s1 = -3.0e38f;
  if (t <= li) {
    const short8* kr = (const short8*)&kvL[t*KVS];
    float a00=0.f,a01=0.f,a10=0.f,a11=0.f;
#pragma unroll
    for (int kk = 0; kk < 4; kk++) {
      short8 k0 = kr[kk*2], k1 = kr[kk*2+1], k2 = kr[8+kk*2], k3 = kr[8+kk*2+1];
#pragma unroll
      for (int j = 0; j < 8; j++) {
        a00 += qv[kk*16 + j]      * us2f((unsigned short)k0[j]);
        a01 += qv[kk*16 + 8 + j]  * us2f((unsigned short)k1[j]);
        a10 += qv[64 + kk*16 + j]     * us2f((unsigned short)k2[j]);
        a11 += qv[64 + kk*16 + 8 + j] * us2f((unsigned short)k3[j]);
      }
    }
    s0 = (a00+a01) * 0.125f; s1 = (a10+a11) * 0.125f;
  }
  float m0 = wave_max(s0), m1 = wave_max(s1);
  if (ln == 0) { sred[w] = m0; sred[4+w] = m1; }
  __syncthreads();
  m0 = fmaxf(fmaxf(sred[0],sred[1]), fmaxf(sred[2],sred[3]));
  m1 = fmaxf(fmaxf(sred[4],sred[5]), fmaxf(sred[6],sred[7]));
  __syncthreads();
  float e0 = (t <= li) ? __expf(s0 - m0) : 0.f;
  float e1 = (t <= li) ? __expf(s1 - m1) : 0.f;
  pb0[t] = e0; pb1[t] = e1;
  float l0 = wave_sum(e0), l1 = wave_sum(e1);
  if (ln == 0) { sred[w] = l0; sred[4+w] = l1; }
  __syncthreads();
  l0 = sred[0]+sred[1]+sred[2]+sred[3];
  l1 = sred[4]+sred[5]+sred[6]+sred[7];
  {
    int part = t >> 5, cq = t & 31, ch = cq * 4;
    int cnt = li + 1, cpp = (cnt + 7) >> 3;
    int j0 = part * cpp, j1 = min(j0 + cpp, cnt);
    const float* pbh = (ch < 64) ? pb0 : pb1;
    float a0=0.f,a1=0.f,a2=0.f,a3=0.f;
#pragma unroll 4
    for (int j = j0; j < j1; j++) {
      ushort4v v4 = *(const ushort4v*)&kvL[j*KVS + 128 + ch];
      float pw = pbh[j];
      a0 += pw*us2f(v4.x); a1 += pw*us2f(v4.y); a2 += pw*us2f(v4.z); a3 += pw*us2f(v4.w);
    }
    floatx4 o = {a0,a1,a2,a3};
    av4[part*32 + cq] = o;
  }
  __syncthreads();
  if (c < 128) {
    float l = (c < 64) ? l0 : l1;
    float acc = 0.f;
#pragma unroll
    for (int pp = 0; pp < 8; pp++) acc += ((const float*)&av4[pp*32 + (c>>2)])[c&3];
    aout[c] = acc / l;
  }
  __syncthreads();
  float x2v = 0.f;
  if (c < 128) x2v = qin[c] + p.cbo[c] + dot128i(p.cWo + c*128, aout);
  s = wave_sum((c<128)?x2v:0.f); s2 = wave_sum((c<128)?x2v*x2v:0.f);
  if (ln == 0) { sred[w] = s; sred[4+w] = s2; }
  __syncthreads();
  mu = (sred[0]+sred[1]+sred[2]+sred[3]) * (1.f/128.f);
  ms = (sred[4]+sred[5]+sred[6]+sred[7]) * (1.f/128.f);
  rs = rsqrtf(fmaxf(ms - mu*mu, 0.f) + 1e-5f);
  __syncthreads();
  if (c < 128) hh[c] = (x2v - mu) * rs * p.cln[256+c] + p.cln[384+c];
  __syncthreads();
  if (c < 128) f1[c] = fmaxf(p.cb1[c] + dot128i(p.cW1 + c*128, hh), 0.f);
  __syncthreads();
  float x3v = 0.f;
  if (c < 128) x3v = hh[c] + p.cb2[c] + dot128i(p.cW2 + c*128, f1);
  s = wave_sum((c<128)?x3v:0.f); s2 = wave_sum((c<128)?x3v*x3v:0.f);
  if (ln == 0) { sred[w] = s; sred[4+w] = s2; }
  __syncthreads();
  mu = (sred[0]+sred[1]+sred[2]+sred[3]) * (1.f/128.f);
  ms = (sred[4]+sred[5]+sred[6]+sred[7]) * (1.f/128.f);
  rs = rsqrtf(fmaxf(ms - mu*mu, 0.f) + 1e-5f);
  if (c < 128) {
    float lf = (x3v - mu) * rs * p.cln[512+c] + p.cln[640+c];
    float outv = 0.6f * lf + 0.4f * htL[c];
    if (f32) ((float*)p.out)[b*Dd + c] = outv;
    else     ((bf16*)p.out)[b*Dd + c]  = f2b(outv);
  }
}

// ---------------------------------------------------------------- host
extern "C" void kernel_launch(void* const* d_in, const int* in_sizes, int n_in,
                              void* d_out, int out_size, void* d_ws, size_t ws_size,
                              hipStream_t stream)
{
  (void)in_sizes; (void)n_in; (void)out_size; (void)ws_size;
  const void* item_emb = d_in[0];
  const int* seqs = (const int*)d_in[30];
  const int* lens = (const int*)d_in[31];

  char* wsp = (char*)d_ws;
  size_t o = 0;
  auto alloc = [&](size_t sz) { void* p = wsp + o; o += (sz + 255) & ~(size_t)255; return p; };
  int*      alias_g = (int*)alloc((size_t)BL*4);
  int*      items_g = (int*)alloc((size_t)BL*4);
  float*    rin_g   = (float*)alloc((size_t)BL*4);
  float*    rout_g  = (float*)alloc((size_t)BL*4);
  unsigned* adj_g   = (unsigned*)alloc((size_t)BL*8*4);
  unsigned* adjT_g  = (unsigned*)alloc((size_t)BL*8*4);
  // cWhe and cWhh MUST be adjacent (merged he+gh dispatch reads 640 rows from cWhe).
  bf16*     cWhe    = (bf16*)alloc(32768*2);     // 65536 B, 256-aligned
  bf16*     cWhh    = (bf16*)alloc(49152*2);
  bf16*     cWih    = (bf16*)alloc(98304*2);
  bf16*     cWkv    = (bf16*)alloc(32768*2);
  bf16*     cWq     = (bf16*)alloc(16384*2);
  bf16*     cWo     = (bf16*)alloc(16384*2);
  bf16*     cW1     = (bf16*)alloc(16384*2);
  bf16*     cW2     = (bf16*)alloc(16384*2);
  bf16*     cPos    = (bf16*)alloc(25600*2);
  // bias_he and bias_gh MUST be adjacent (merged bias[640]).
  float*    bias_he = (float*)alloc(256*4);      // 1024 B
  float*    bias_gh = (float*)alloc(384*4);
  float*    bias_gi = (float*)alloc(384*4);
  float*    bias_kv = (float*)alloc(256*4);
  float*    cbq     = (float*)alloc(128*4);
  float*    cbo     = (float*)alloc(128*4);
  float*    cb1     = (float*)alloc(128*4);
  float*    cb2     = (float*)alloc(128*4);
  float*    cbiah   = (float*)alloc(128*4);
  float*    cboah   = (float*)alloc(128*4);
  float*    cln     = (float*)alloc(768*4);
  bf16*     he      = (bf16*)alloc((size_t)BL*256*2);
  bf16*     hio     = (bf16*)alloc((size_t)BL*256*2);
  bf16*     gi      = (bf16*)alloc((size_t)BL*384*2);
  bf16*     gh      = (bf16*)alloc((size_t)BL*384*2);

  PackP pp = { d_in[2], d_in[4], d_in[8], d_in[10], d_in[16], d_in[18], d_in[14], d_in[20],
               d_in[24], d_in[26], d_in[1],
               d_in[3], d_in[5], d_in[9], d_in[11], d_in[17], d_in[19], d_in[15], d_in[21],
               d_in[25], d_in[27], d_in[6], d_in[7],
               d_in[12], d_in[13], d_in[22], d_in[23], d_in[28], d_in[29],
               cWhe, cWih, cWhh, cWkv, cWq, cWo, cW1, cW2, cPos,
               bias_he, bias_gi, bias_gh, bias_kv, cbq, cbo, cb1, cb2, cbiah, cboah, cln,
               seqs, alias_g, items_g, rin_g, rout_g, adj_g, adjT_g };
  k01<<<Bb + 1199, 256, 0, stream>>>(pp);
  // G1: he (N=256) + gh (N=384), A gathered ONCE per m-block, 5 n-tiles in-kernel
  gemm_he2<<<BL/128, 256, 0, stream>>>(item_emb, items_g, cWhe, bias_he, he, 256, gh, 384, 256);
  k3_agg<<<Bb*25, 256, 0, stream>>>(he, adj_g, adjT_g, rin_g, rout_g, cbiah, cboah, hio);
  // G2: gi (K=256, N=384)
  gemm6<256><<<dim3(BL/128, 3), 256, 0, stream>>>(hio, cWih, bias_gi, gi, 384, gi, 384, 1<<30);
  // KV+ATTN fused: GRU + gather + pos + kv-GEMM (LDS-resident) + attention tail per batch
  KAP kp = { gi, gh, item_emb, seqs, alias_g, lens, cPos, cWkv, bias_kv,
             cWq, cWo, cW1, cW2, cbq, cbo, cb1, cb2, cln, d_out };
  kv_attn<<<Bb, 256, 0, stream>>>(kp);
}

// Round 16
// 259.461 us; speedup vs baseline: 1.0447x; 1.0434x over previous
//
#include <hip/hip_runtime.h>
#include <hip/hip_bf16.h>

#define Bb 256
#define Ll 200
#define Dd 128
#define BL (Bb*Ll)
#define KVS 264   // kvL row stride in shorts: 528 B, 16-B ALIGNED (b128-friendly).
                  // 8-way bank aliasing on row-indexed reads costs only ~0.7us total
                  // (447K conflict-cycles / 256 CU); misaligned odd-dword strides cost
                  // ~6us from split ds ops (measured r13=41.2 vs r14/15=47.5-48.7).

typedef __hip_bfloat16 bf16;
typedef __attribute__((ext_vector_type(8))) short short8;
typedef __attribute__((ext_vector_type(4))) unsigned short ushort4v;
typedef __attribute__((ext_vector_type(4))) float floatx4;

__device__ __forceinline__ float b2f(bf16 v) { return __bfloat162float(v); }
__device__ __forceinline__ bf16  f2b(float v) { return __float2bfloat16(v); }
__device__ __forceinline__ float us2f(unsigned short u) { return __uint_as_float(((unsigned)u) << 16); }
__device__ __forceinline__ unsigned short f2us(float v) { bf16 t = f2b(v); return *(unsigned short*)&t; }
__device__ __forceinline__ float ldf(const void* p, int i, int f32) {
  return f32 ? ((const float*)p)[i] : b2f(((const bf16*)p)[i]);
}
// dtype probe: uniform(-.088,.088) bf16 never has exp>=0x7F; f32 mantissa halves do ~50%.
__device__ __forceinline__ int detect_f32(const unsigned short* __restrict__ w) {
  unsigned short u = w[threadIdx.x & 63];
  return (__ballot(((u >> 7) & 0xFF) >= 0x7F) != 0ull) ? 1 : 0;
}
// async global->LDS DMA, 16B per lane; LDS dest = wave-uniform base + lane*16
__device__ __forceinline__ void load_lds16(const void* g, void* l) {
  __builtin_amdgcn_global_load_lds((const __attribute__((address_space(1))) unsigned int*)g,
                                   (__attribute__((address_space(3))) unsigned int*)l, 16, 0, 0);
}
// gather one 8-elem chunk (cols 8g..8g+7) of emb row `it`, dtype-aware, as bf16x8 (vectorized)
__device__ __forceinline__ short8 emb_chunk8(const void* __restrict__ emb, int it, int g, int f32) {
  short8 o;
  if (f32) {
    const float4* e = (const float4*)((const float*)emb + (size_t)it * 128 + g * 8);
    float4 a = e[0], b = e[1];
    o[0] = (short)f2us(a.x); o[1] = (short)f2us(a.y); o[2] = (short)f2us(a.z); o[3] = (short)f2us(a.w);
    o[4] = (short)f2us(b.x); o[5] = (short)f2us(b.y); o[6] = (short)f2us(b.z); o[7] = (short)f2us(b.w);
  } else {
    o = ((const short8*)((const bf16*)emb + (size_t)it * 128))[g];
  }
  return o;
}

// ---------------------------------------------------------------- K01: graph build (blocks 0..255) + pack (rest)
struct PackP {
  const void *W_ei,*W_eo,*w_ih,*w_hh,*Wk,*Wv,*Wqp,*Wop,*W1p,*W2p,*pos;
  const void *b_ei,*b_eo,*b_ih,*b_hh,*bk,*bv,*bqp,*bop,*b1p,*b2p,*biah,*boah;
  const void *ln1g,*ln1b,*ln2g,*ln2b,*lnfg,*lnfb;
  bf16 *cWhe,*cWih,*cWhh,*cWkv,*cWq,*cWo,*cW1,*cW2,*cPos;
  float *bias_he,*bias_gi,*bias_gh,*bias_kv,*cbq,*cbo,*cb1,*cb2,*cbiah,*cboah,*cln;
  const int* seqs;
  int *alias_g, *items_g; float *rin_g, *rout_g; unsigned *adj_g, *adjT_g;
};
__global__ __launch_bounds__(256) void k01(PackP p) {
  __shared__ alignas(16) int s[Ll];
  __shared__ int al[Ll], its[Ll];
  __shared__ alignas(4) unsigned char isf[Ll];
  __shared__ unsigned adjL[Ll*8], adjTL[Ll*8];
  if (blockIdx.x >= Bb) {
    int idx = (blockIdx.x - Bb) * 256 + threadIdx.x;       // < 306944
    int f32 = detect_f32((const unsigned short*)p.W_ei);
    if (idx < 131072) {
      if (idx < 32768) {
        int r = idx >> 7, c = idx & 127;
        p.cWhe[idx] = f2b(r < 128 ? ldf(p.W_ei, r*128+c, f32) : ldf(p.W_eo, (r-128)*128+c, f32));
      } else p.cWih[idx-32768] = f2b(ldf(p.w_ih, idx-32768, f32));
    } else if (idx < 278528) {
      if (idx < 180224)      p.cWhh[idx-131072] = f2b(ldf(p.w_hh, idx-131072, f32));
      else if (idx < 212992) {
        int i = idx - 180224; int r = i >> 7, c = i & 127;
        p.cWkv[i] = f2b(r < 128 ? ldf(p.Wk, r*128+c, f32) : ldf(p.Wv, (r-128)*128+c, f32));
      }
      else if (idx < 229376) p.cWq[idx-212992] = f2b(ldf(p.Wqp, idx-212992, f32));
      else if (idx < 245760) p.cWo[idx-229376] = f2b(ldf(p.Wop, idx-229376, f32));
      else if (idx < 262144) p.cW1[idx-245760] = f2b(ldf(p.W1p, idx-245760, f32));
      else                   p.cW2[idx-262144] = f2b(ldf(p.W2p, idx-262144, f32));
    } else if (idx < 304128) {
      p.cPos[idx-278528] = f2b(ldf(p.pos, idx-278528, f32));
    } else {
      int j = idx - 304128;                          // < 2816
      if      (j < 256)  p.bias_he[j]     = (j<128) ? ldf(p.b_ei,j,f32) : ldf(p.b_eo,j-128,f32);
      else if (j < 640)  p.bias_gi[j-256] = ldf(p.b_ih, j-256, f32);
      else if (j < 1024) p.bias_gh[j-640] = ldf(p.b_hh, j-640, f32);
      else if (j < 1280) { int c=j-1024; p.bias_kv[c] = (c<128)? ldf(p.bk,c,f32): ldf(p.bv,c-128,f32); }
      else if (j < 1408) p.cbq[j-1280]   = ldf(p.bqp, j-1280, f32);
      else if (j < 1536) p.cbo[j-1408]   = ldf(p.bop, j-1408, f32);
      else if (j < 1664) p.cb1[j-1536]   = ldf(p.b1p, j-1536, f32);
      else if (j < 1792) p.cb2[j-1664]   = ldf(p.b2p, j-1664, f32);
      else if (j < 1920) p.cbiah[j-1792] = ldf(p.biah, j-1792, f32);
      else if (j < 2048) p.cboah[j-1920] = ldf(p.boah, j-1920, f32);
      else {
        int i = j - 2048, g = i >> 7, c2 = i & 127;
        const void* s6 = g==0?p.ln1g: g==1?p.ln1b: g==2?p.ln2g: g==3?p.ln2b: g==4?p.lnfg: p.lnfb;
        p.cln[i] = ldf(s6, c2, f32);
      }
    }
    return;
  }
  // ---- graph part (one block per batch row), int4-vectorized inner loops
  int b = blockIdx.x, t = threadIdx.x;
  if (t < Ll) s[t] = p.seqs[b*Ll + t];
  for (int i = t; i < Ll*8; i += 256) { adjL[i] = 0u; adjTL[i] = 0u; }
  __syncthreads();
  const int4* s4 = (const int4*)s;
  if (t < Ll) {
    int v = s[t]; int dup = 0;
    int nb = t >> 2;
    for (int j4 = 0; j4 < nb; j4++) {
      int4 sv = s4[j4];
      dup |= (sv.x==v) | (sv.y==v) | (sv.z==v) | (sv.w==v);
    }
    for (int j = nb*4; j < t; j++) dup |= (s[j]==v);
    isf[t] = dup ? 0 : 1; its[t] = 0;
  }
  __syncthreads();
  const unsigned* isfw = (const unsigned*)isf;
  if (t < Ll) {
    int v = s[t], r = 0;
    for (int j4 = 0; j4 < Ll/4; j4++) {
      int4 sv = s4[j4];
      unsigned fw = isfw[j4];
      r += ((fw & 0xffu)       && sv.x < v);
      r += ((fw & 0xff00u)     && sv.y < v);
      r += ((fw & 0xff0000u)   && sv.z < v);
      r += ((fw & 0xff000000u) && sv.w < v);
    }
    al[t] = r;
  }
  __syncthreads();
  if (t < Ll && isf[t]) its[al[t]] = s[t];
  if (t < Ll-1 && s[t+1] > 0) {
    int u = al[t], v = al[t+1];
    atomicOr(&adjL [u*8 + (v >> 5)], 1u << (v & 31));
    atomicOr(&adjTL[v*8 + (u >> 5)], 1u << (u & 31));
  }
  __syncthreads();
  if (t < Ll) {
    int od = 0, id = 0;
    for (int wd = 0; wd < 7; wd++) { od += __popc(adjL[t*8+wd]); id += __popc(adjTL[t*8+wd]); }
    p.rout_g [b*Ll + t] = 1.0f / (float)max(od, 1);
    p.rin_g  [b*Ll + t] = 1.0f / (float)max(id, 1);
    p.alias_g[b*Ll + t] = al[t];
    p.items_g[b*Ll + t] = its[t];
  }
  for (int i = t; i < Ll*8; i += 256) { p.adj_g[b*Ll*8 + i] = adjL[i]; p.adjT_g[b*Ll*8 + i] = adjTL[i]; }
}

// ---------------------------------------------------------------- GEMM-HE v2: A gathered ONCE, loop over 5 n-tiles
__global__ __launch_bounds__(256) void gemm_he2(const void* __restrict__ emb, const int* __restrict__ items_g,
    const bf16* __restrict__ W, const float* __restrict__ bias,
    bf16* __restrict__ out_lo, int Nlo, bf16* __restrict__ out_hi, int Nhi, int split)
{
  __shared__ short As[128*128];                 // 32 KB
  __shared__ short Ws[128*128];                 // 32 KB
  int t = threadIdx.x;
  int wave = t >> 6, lane = t & 63;
  int q = lane >> 4, mr = lane & 15;
  int wm = wave & 1, wn = wave >> 1;
  int m0 = blockIdx.x * 128;
  int f32 = detect_f32((const unsigned short*)emb);
  {
    int r = t >> 1, half = t & 1;
    int it = items_g[m0 + r];
#pragma unroll
    for (int g8 = 0; g8 < 8; g8++) {
      int g = half*8 + g8;
      short8 o = emb_chunk8(emb, it, g, f32);
      *(short8*)&As[r*128 + (g ^ (r & 15))*8] = o;
    }
  }
  int srow = lane >> 4, c16 = lane & 15;
  for (int nt = 0; nt < 5; nt++) {
    int n0 = nt * 128;
#pragma unroll
    for (int i = 0; i < 8; i++) {
      int seg = wave*8 + i;
      int r = seg*4 + srow;
      int gch = c16 ^ (r & 15);
      load_lds16(W + (size_t)(n0 + r) * 128 + gch*8, &Ws[seg*512]);
    }
    __syncthreads();
    floatx4 acc[4][4] = {};
#pragma unroll
    for (int kk = 0; kk < 4; kk++) {
      short8 af[4], wf[4];
#pragma unroll
      for (int i = 0; i < 4; i++) {
        int row = wm*64 + i*16 + mr;
        af[i] = *(const short8*)(&As[row*128 + ((kk*4+q) ^ (row&15))*8]);
      }
#pragma unroll
      for (int j = 0; j < 4; j++) {
        int row = wn*64 + j*16 + mr;
        wf[j] = *(const short8*)(&Ws[row*128 + ((kk*4+q) ^ (row&15))*8]);
      }
#pragma unroll
      for (int i = 0; i < 4; i++)
#pragma unroll
        for (int j = 0; j < 4; j++)
          acc[i][j] = __builtin_amdgcn_mfma_f32_16x16x32_bf16(wf[j], af[i], acc[i][j], 0, 0, 0);
    }
#pragma unroll
    for (int j = 0; j < 4; j++) {
      int ng = n0 + wn*64 + j*16 + q*4;
      floatx4 bs = *(const floatx4*)(bias + ng);
      bf16* outp; int col, stride;
      if (ng < split) { outp = out_lo; col = ng; stride = Nlo; }
      else            { outp = out_hi; col = ng - split; stride = Nhi; }
#pragma unroll
      for (int i = 0; i < 4; i++) {
        int m = m0 + wm*64 + i*16 + mr;
        ushort4v o;
#pragma unroll
        for (int e = 0; e < 4; e++) o[e] = f2us(acc[i][j][e] + bs[e]);
        *(ushort4v*)(outp + (size_t)m * stride + col) = o;
      }
    }
    if (nt + 1 < 5) __syncthreads();
  }
}

// ---------------------------------------------------------------- MFMA GEMM v6 (used for gi: K=256)
template<int K>
__global__ __launch_bounds__(256) void gemm6(const bf16* __restrict__ A, const bf16* __restrict__ W,
    const float* __restrict__ bias,
    bf16* __restrict__ out_lo, int Nlo, bf16* __restrict__ out_hi, int Nhi, int split)
{
  __shared__ short As[128*128];                 // 32 KB
  __shared__ short Ws[128*128];                 // 32 KB
  int t = threadIdx.x;
  int wave = t >> 6, lane = t & 63;
  int q = lane >> 4, mr = lane & 15;
  int wm = wave & 1, wn = wave >> 1;
  int m0 = blockIdx.x * 128, n0 = blockIdx.y * 128;
  int srow = lane >> 4;
  int c16 = lane & 15;
  floatx4 acc[4][4] = {};
  for (int k0 = 0; k0 < K; k0 += 128) {
#pragma unroll
    for (int i = 0; i < 8; i++) {
      int seg = wave*8 + i;
      int r = seg*4 + srow;
      int gch = c16 ^ (r & 15);
      load_lds16(A + (size_t)(m0 + r) * K + k0 + gch*8, &As[seg*512]);
      load_lds16(W + (size_t)(n0 + r) * K + k0 + gch*8, &Ws[seg*512]);
    }
    __syncthreads();
#pragma unroll
    for (int kk = 0; kk < 4; kk++) {
      short8 af[4], wf[4];
#pragma unroll
      for (int i = 0; i < 4; i++) {
        int row = wm*64 + i*16 + mr;
        af[i] = *(const short8*)(&As[row*128 + ((kk*4+q) ^ (row&15))*8]);
      }
#pragma unroll
      for (int j = 0; j < 4; j++) {
        int row = wn*64 + j*16 + mr;
        wf[j] = *(const short8*)(&Ws[row*128 + ((kk*4+q) ^ (row&15))*8]);
      }
#pragma unroll
      for (int i = 0; i < 4; i++)
#pragma unroll
        for (int j = 0; j < 4; j++)
          acc[i][j] = __builtin_amdgcn_mfma_f32_16x16x32_bf16(wf[j], af[i], acc[i][j], 0, 0, 0);
    }
    if (k0 + 128 < K) __syncthreads();
  }
#pragma unroll
  for (int j = 0; j < 4; j++) {
    int ng = n0 + wn*64 + j*16 + q*4;
    floatx4 bs = *(const floatx4*)(bias + ng);
    bf16* outp; int col, stride;
    if (ng < split) { outp = out_lo; col = ng; stride = Nlo; }
    else            { outp = out_hi; col = ng - split; stride = Nhi; }
#pragma unroll
    for (int i = 0; i < 4; i++) {
      int m = m0 + wm*64 + i*16 + mr;
      ushort4v o;
#pragma unroll
      for (int e = 0; e < 4; e++) o[e] = f2us(acc[i][j][e] + bs[e]);
      *(ushort4v*)(outp + (size_t)m * stride + col) = o;
    }
  }
}

// ---------------------------------------------------------------- K3: sparse graph aggregation (one wave per node)
__global__ __launch_bounds__(256) void k3_agg(const bf16* __restrict__ he,
    const unsigned* __restrict__ adj_g, const unsigned* __restrict__ adjT_g,
    const float* __restrict__ rin_g, const float* __restrict__ rout_g,
    const float* __restrict__ cbiah, const float* __restrict__ cboah, bf16* __restrict__ hio)
{
  int b = blockIdx.x / 25, chunk = blockIdx.x % 25;
  int wave = threadIdx.x >> 6, lane = threadIdx.x & 63;
  bool isIn = lane < 32;
  int c = isIn ? 4*lane : 128 + 4*(lane-32);
  const bf16* heb = he + (size_t)b * Ll * 256;
  bf16* hiob = hio + (size_t)b * Ll * 256;
  float bias0 = isIn ? cbiah[c]   : cboah[c-128];
  float bias1 = isIn ? cbiah[c+1] : cboah[c-127];
  float bias2 = isIn ? cbiah[c+2] : cboah[c-126];
  float bias3 = isIn ? cbiah[c+3] : cboah[c-125];
#pragma unroll
  for (int s = 0; s < 2; s++) {
    int i = chunk*8 + wave + 4*s;
    const unsigned* mrow = (isIn ? adjT_g : adj_g) + ((size_t)b*Ll + i) * 8;
    float a0=0.f, a1=0.f, a2=0.f, a3=0.f;
    for (int wd = 0; wd < 7; wd++) {
      unsigned bits = mrow[wd];
      while (bits) {
        int j = (wd << 5) + __builtin_ctz(bits); bits &= bits - 1;
        ushort4v h4 = *(const ushort4v*)(heb + (size_t)j*256 + c);
        a0 += us2f(h4.x); a1 += us2f(h4.y); a2 += us2f(h4.z); a3 += us2f(h4.w);
      }
    }
    float r = isIn ? rin_g[b*Ll + i] : rout_g[b*Ll + i];
    ushort4v o;
    o.x = f2us(bias0 + r*a0); o.y = f2us(bias1 + r*a1);
    o.z = f2us(bias2 + r*a2); o.w = f2us(bias3 + r*a3);
    *(ushort4v*)(hiob + (size_t)i*256 + c) = o;
  }
}

// ---------------------------------------------------------------- KV+ATTN fused (r13 layout): aligned stride-264 kvL
// LDS pool (162,688 <= 163,840): xs 56,576 | kvL 200x264 shorts 105,600 | htL 512.
struct KAP {
  const bf16 *gi, *gh; const void* emb; const int* seqs; const int* alias_g; const int* lens;
  const bf16 *cPos, *cWkv; const float* bias_kv;
  const bf16 *cWq, *cWo, *cW1, *cW2;
  const float *cbq, *cbo, *cb1, *cb2, *cln;
  void* out;
};
__device__ __forceinline__ float dot128i(const bf16* __restrict__ wrow, const float* __restrict__ vin) {
  const short8* wr = (const short8*)wrow;
  float a0=0.f, a1=0.f, a2=0.f, a3=0.f;
#pragma unroll
  for (int kk = 0; kk < 4; kk++) {
    short8 w0 = wr[kk*4+0], w1 = wr[kk*4+1], w2 = wr[kk*4+2], w3 = wr[kk*4+3];
#pragma unroll
    for (int j = 0; j < 8; j++) {
      a0 += vin[kk*32 +      j] * us2f((unsigned short)w0[j]);
      a1 += vin[kk*32 + 8  + j] * us2f((unsigned short)w1[j]);
      a2 += vin[kk*32 + 16 + j] * us2f((unsigned short)w2[j]);
      a3 += vin[kk*32 + 24 + j] * us2f((unsigned short)w3[j]);
    }
  }
  return (a0+a1)+(a2+a3);
}
__device__ __forceinline__ float wave_sum(float v) {
#pragma unroll
  for (int m = 1; m < 64; m <<= 1) v += __shfl_xor(v, m, 64);
  return v;
}
__device__ __forceinline__ float wave_max(float v) {
#pragma unroll
  for (int m = 1; m < 64; m <<= 1) v = fmaxf(v, __shfl_xor(v, m, 64));
  return v;
}
__global__ __launch_bounds__(256) void kv_attn(KAP p)
{
  __shared__ __align__(16) char pool[162688];
  short* xs   = (short*)pool;                      // 208*136 shorts (dead after phase B)
  short* kvL  = (short*)(pool + 56576);            // 200 rows x KVS elems (528 B, aligned)
  float* htL  = (float*)(pool + 56576 + 105600);   // 128 floats
  int* aliasL = (int*)(pool + 56576);              // overlay: dead before phase B writes
  int* seqL   = aliasL + 200;
  // k7-part scratch overlays xs (valid after post-phase-B barrier)
  float* qin  = (float*)pool;
  float* qv   = qin + 128;
  float* aout = qv + 128;
  float* hh   = aout + 128;
  float* f1   = hh + 128;
  float* pb0  = f1 + 128;                          // 256
  float* pb1  = pb0 + 256;                         // 256
  floatx4* av4 = (floatx4*)(pb1 + 256);            // 8*32 floatx4 (offset 4608, 16B aligned)
  float* sred = (float*)(av4 + 8*32);              // 8

  int b = blockIdx.x, t = threadIdx.x;
  int wave = t >> 6, lane = t & 63, q = lane >> 4, mr = lane & 15;
  int li = p.lens[b] - 1;
  int f32 = detect_f32((const unsigned short*)p.emb);
  if (t < Ll) { aliasL[t] = p.alias_g[b*Ll + t]; seqL[t] = p.seqs[b*Ll + t]; }
  for (int u = t; u < 8*136; u += 256) xs[Ll*136 + u] = 0;   // zero pad rows 200..207
  __syncthreads();
  // ---- phase A: xs[tpos] = GRU(gates at alias[tpos], h = emb[seqs[tpos]]) + pos[tpos]; ht -> htL
  for (int u = t; u < Ll*16; u += 256) {
    int tpos = u >> 4, jv = u & 15;
    int a = aliasL[tpos];
    int it = seqL[tpos];
    const short8* gin = (const short8*)(p.gi + ((size_t)b*Ll + a) * 384);
    const short8* ghn = (const short8*)(p.gh + ((size_t)b*Ll + a) * 384);
    short8 vir = gin[jv], vii = gin[16+jv], vnn = gin[32+jv];
    short8 whr = ghn[jv], whi = ghn[16+jv], whn = ghn[32+jv];
    short8 hv  = emb_chunk8(p.emb, it, jv, f32);
    short8 pv  = ((const short8*)(p.cPos + tpos * Dd))[jv];
    bool isLast = (tpos == li);
    short8 o;
#pragma unroll
    for (int e = 0; e < 8; e++) {
      float ir = us2f((unsigned short)vir[e]), ii = us2f((unsigned short)vii[e]), inn = us2f((unsigned short)vnn[e]);
      float hr = us2f((unsigned short)whr[e]), hi = us2f((unsigned short)whi[e]), hn = us2f((unsigned short)whn[e]);
      float r  = 1.f / (1.f + __expf(-(ir + hr)));
      float z  = 1.f / (1.f + __expf(-(ii + hi)));
      float arg = inn + r * hn;
      float ex = __expf(-2.f * arg);
      float ng = (1.f - ex) / (1.f + ex);
      float h  = us2f((unsigned short)hv[e]);
      float sh = ng + z * (h - ng);
      o[e] = (short)f2us(sh + us2f((unsigned short)pv[e]));
      if (isLast) htL[jv*8 + e] = sh;
    }
    *(short8*)&xs[tpos*136 + jv*8] = o;
  }
  __syncthreads();                                 // aliasL/seqL dead from here
  // ---- phase B: kvL = xs @ Wkv^T + bias (per-wave n-quadrant), written to LDS
  {
    short8 wf[4][4];
#pragma unroll
    for (int kk = 0; kk < 4; kk++)
#pragma unroll
      for (int j = 0; j < 4; j++) {
        int n = wave*64 + j*16 + mr;
        wf[kk][j] = *(const short8*)(p.cWkv + (size_t)n*128 + kk*32 + q*8);
      }
    for (int mt = 0; mt < 13; mt++) {
      short8 af[4];
#pragma unroll
      for (int kk = 0; kk < 4; kk++)
        af[kk] = *(const short8*)&xs[(mt*16 + mr)*136 + (kk*4+q)*8];
      floatx4 acc[4] = {};
#pragma unroll
      for (int kk = 0; kk < 4; kk++)
#pragma unroll
        for (int j = 0; j < 4; j++)
          acc[j] = __builtin_amdgcn_mfma_f32_16x16x32_bf16(wf[kk][j], af[kk], acc[j], 0, 0, 0);
      int m = mt*16 + mr;
      if (m < Ll) {
#pragma unroll
        for (int j = 0; j < 4; j++) {
          int n = wave*64 + j*16 + q*4;
          floatx4 bs = *(const floatx4*)(p.bias_kv + n);
          ushort4v o;
#pragma unroll
          for (int e = 0; e < 4; e++) o[e] = f2us(acc[j][e] + bs[e]);
          *(ushort4v*)&kvL[m*KVS + n] = o;
        }
      }
    }
  }
  __syncthreads();                                 // xs dead from here; kvL ready
  // ---- attention tail: x[li] = htL + pos[li]
  int c = t, w = wave, ln = lane;
  float xv = (c < 128) ? (htL[c] + b2f(p.cPos[li*Dd + c])) : 0.f;
  float s = wave_sum(xv), s2 = wave_sum(xv*xv);
  if (ln == 0) { sred[w] = s; sred[4+w] = s2; }
  __syncthreads();
  float mu = (sred[0]+sred[1]+sred[2]+sred[3]) * (1.f/128.f);
  float ms = (sred[4]+sred[5]+sred[6]+sred[7]) * (1.f/128.f);
  float rs = rsqrtf(fmaxf(ms - mu*mu, 0.f) + 1e-5f);
  __syncthreads();
  if (c < 128) qin[c] = (xv - mu) * rs * p.cln[c] + p.cln[128+c];
  __syncthreads();
  if (c < 128) qv[c] = p.cbq[c] + dot128i(p.cWq + c*128, qin);
  __syncthreads();
  float s0 = -3.0e38f, s1 = -3.0e38f;
  if (t <= li) {
    const short8* kr = (const short8*)&kvL[t*KVS];
    float a00=0.f,a01=0.f,a10=0.f,a11=0.f;
#pragma unroll
    for (int kk = 0; kk < 4; kk++) {
      short8 k0 = kr[kk*2], k1 = kr[kk*2+1], k2 = kr[8+kk*2], k3 = kr[8+kk*2+1];
#pragma unroll
      for (int j = 0; j < 8; j++) {
        a00 += qv[kk*16 + j]      * us2f((unsigned short)k0[j]);
        a01 += qv[kk*16 + 8 + j]  * us2f((unsigned short)k1[j]);
        a10 += qv[64 + kk*16 + j]     * us2f((unsigned short)k2[j]);
        a11 += qv[64 + kk*16 + 8 + j] * us2f((unsigned short)k3[j]);
      }
    }
    s0 = (a00+a01) * 0.125f; s1 = (a10+a11) * 0.125f;
  }
  float m0 = wave_max(s0), m1 = wave_max(s1);
  if (ln == 0) { sred[w] = m0; sred[4+w] = m1; }
  __syncthreads();
  m0 = fmaxf(fmaxf(sred[0],sred[1]), fmaxf(sred[2],sred[3]));
  m1 = fmaxf(fmaxf(sred[4],sred[5]), fmaxf(sred[6],sred[7]));
  __syncthreads();
  float e0 = (t <= li) ? __expf(s0 - m0) : 0.f;
  float e1 = (t <= li) ? __expf(s1 - m1) : 0.f;
  pb0[t] = e0; pb1[t] = e1;
  float l0 = wave_sum(e0), l1 = wave_sum(e1);
  if (ln == 0) { sred[w] = l0; sred[4+w] = l1; }
  __syncthreads();
  l0 = sred[0]+sred[1]+sred[2]+sred[3];
  l1 = sred[4]+sred[5]+sred[6]+sred[7];
  {
    int part = t >> 5, cq = t & 31, ch = cq * 4;
    int cnt = li + 1, cpp = (cnt + 7) >> 3;
    int j0 = part * cpp, j1 = min(j0 + cpp, cnt);
    const float* pbh = (ch < 64) ? pb0 : pb1;
    float a0=0.f,a1=0.f,a2=0.f,a3=0.f;
#pragma unroll 4
    for (int j = j0; j < j1; j++) {
      ushort4v v4 = *(const ushort4v*)&kvL[j*KVS + 128 + ch];
      float pw = pbh[j];
      a0 += pw*us2f(v4.x); a1 += pw*us2f(v4.y); a2 += pw*us2f(v4.z); a3 += pw*us2f(v4.w);
    }
    floatx4 o = {a0,a1,a2,a3};
    av4[part*32 + cq] = o;
  }
  __syncthreads();
  if (c < 128) {
    float l = (c < 64) ? l0 : l1;
    float acc = 0.f;
#pragma unroll
    for (int pp = 0; pp < 8; pp++) acc += ((const float*)&av4[pp*32 + (c>>2)])[c&3];
    aout[c] = acc / l;
  }
  __syncthreads();
  float x2v = 0.f;
  if (c < 128) x2v = qin[c] + p.cbo[c] + dot128i(p.cWo + c*128, aout);
  s = wave_sum((c<128)?x2v:0.f); s2 = wave_sum((c<128)?x2v*x2v:0.f);
  if (ln == 0) { sred[w] = s; sred[4+w] = s2; }
  __syncthreads();
  mu = (sred[0]+sred[1]+sred[2]+sred[3]) * (1.f/128.f);
  ms = (sred[4]+sred[5]+sred[6]+sred[7]) * (1.f/128.f);
  rs = rsqrtf(fmaxf(ms - mu*mu, 0.f) + 1e-5f);
  __syncthreads();
  if (c < 128) hh[c] = (x2v - mu) * rs * p.cln[256+c] + p.cln[384+c];
  __syncthreads();
  if (c < 128) f1[c] = fmaxf(p.cb1[c] + dot128i(p.cW1 + c*128, hh), 0.f);
  __syncthreads();
  float x3v = 0.f;
  if (c < 128) x3v = hh[c] + p.cb2[c] + dot128i(p.cW2 + c*128, f1);
  s = wave_sum((c<128)?x3v:0.f); s2 = wave_sum((c<128)?x3v*x3v:0.f);
  if (ln == 0) { sred[w] = s; sred[4+w] = s2; }
  __syncthreads();
  mu = (sred[0]+sred[1]+sred[2]+sred[3]) * (1.f/128.f);
  ms = (sred[4]+sred[5]+sred[6]+sred[7]) * (1.f/128.f);
  rs = rsqrtf(fmaxf(ms - mu*mu, 0.f) + 1e-5f);
  if (c < 128) {
    float lf = (x3v - mu) * rs * p.cln[512+c] + p.cln[640+c];
    float outv = 0.6f * lf + 0.4f * htL[c];
    if (f32) ((float*)p.out)[b*Dd + c] = outv;
    else     ((bf16*)p.out)[b*Dd + c]  = f2b(outv);
  }
}

// ---------------------------------------------------------------- host
extern "C" void kernel_launch(void* const* d_in, const int* in_sizes, int n_in,
                              void* d_out, int out_size, void* d_ws, size_t ws_size,
                              hipStream_t stream)
{
  (void)in_sizes; (void)n_in; (void)out_size; (void)ws_size;
  const void* item_emb = d_in[0];
  const int* seqs = (const int*)d_in[30];
  const int* lens = (const int*)d_in[31];

  char* wsp = (char*)d_ws;
  size_t o = 0;
  auto alloc = [&](size_t sz) { void* p = wsp + o; o += (sz + 255) & ~(size_t)255; return p; };
  int*      alias_g = (int*)alloc((size_t)BL*4);
  int*      items_g = (int*)alloc((size_t)BL*4);
  float*    rin_g   = (float*)alloc((size_t)BL*4);
  float*    rout_g  = (float*)alloc((size_t)BL*4);
  unsigned* adj_g   = (unsigned*)alloc((size_t)BL*8*4);
  unsigned* adjT_g  = (unsigned*)alloc((size_t)BL*8*4);
  // cWhe and cWhh MUST be adjacent (merged he+gh dispatch reads 640 rows from cWhe).
  bf16*     cWhe    = (bf16*)alloc(32768*2);     // 65536 B, 256-aligned
  bf16*     cWhh    = (bf16*)alloc(49152*2);
  bf16*     cWih    = (bf16*)alloc(98304*2);
  bf16*     cWkv    = (bf16*)alloc(32768*2);
  bf16*     cWq     = (bf16*)alloc(16384*2);
  bf16*     cWo     = (bf16*)alloc(16384*2);
  bf16*     cW1     = (bf16*)alloc(16384*2);
  bf16*     cW2     = (bf16*)alloc(16384*2);
  bf16*     cPos    = (bf16*)alloc(25600*2);
  // bias_he and bias_gh MUST be adjacent (merged bias[640]).
  float*    bias_he = (float*)alloc(256*4);      // 1024 B
  float*    bias_gh = (float*)alloc(384*4);
  float*    bias_gi = (float*)alloc(384*4);
  float*    bias_kv = (float*)alloc(256*4);
  float*    cbq     = (float*)alloc(128*4);
  float*    cbo     = (float*)alloc(128*4);
  float*    cb1     = (float*)alloc(128*4);
  float*    cb2     = (float*)alloc(128*4);
  float*    cbiah   = (float*)alloc(128*4);
  float*    cboah   = (float*)alloc(128*4);
  float*    cln     = (float*)alloc(768*4);
  bf16*     he      = (bf16*)alloc((size_t)BL*256*2);
  bf16*     hio     = (bf16*)alloc((size_t)BL*256*2);
  bf16*     gi      = (bf16*)alloc((size_t)BL*384*2);
  bf16*     gh      = (bf16*)alloc((size_t)BL*384*2);

  PackP pp = { d_in[2], d_in[4], d_in[8], d_in[10], d_in[16], d_in[18], d_in[14], d_in[20],
               d_in[24], d_in[26], d_in[1],
               d_in[3], d_in[5], d_in[9], d_in[11], d_in[17], d_in[19], d_in[15], d_in[21],
               d_in[25], d_in[27], d_in[6], d_in[7],
               d_in[12], d_in[13], d_in[22], d_in[23], d_in[28], d_in[29],
               cWhe, cWih, cWhh, cWkv, cWq, cWo, cW1, cW2, cPos,
               bias_he, bias_gi, bias_gh, bias_kv, cbq, cbo, cb1, cb2, cbiah, cboah, cln,
               seqs, alias_g, items_g, rin_g, rout_g, adj_g, adjT_g };
  k01<<<Bb + 1199, 256, 0, stream>>>(pp);
  // G1: he (N=256) + gh (N=384), A gathered ONCE per m-block, 5 n-tiles in-kernel
  gemm_he2<<<BL/128, 256, 0, stream>>>(item_emb, items_g, cWhe, bias_he, he, 256, gh, 384, 256);
  k3_agg<<<Bb*25, 256, 0, stream>>>(he, adj_g, adjT_g, rin_g, rout_g, cbiah, cboah, hio);
  // G2: gi (K=256, N=384)
  gemm6<256><<<dim3(BL/128, 3), 256, 0, stream>>>(hio, cWih, bias_gi, gi, 384, gi, 384, 1<<30);
  // KV+ATTN fused: GRU + gather + pos + kv-GEMM (LDS-resident) + attention tail per batch
  KAP kp = { gi, gh, item_emb, seqs, alias_g, lens, cPos, cWkv, bias_kv,
             cWq, cWo, cW1, cW2, cbq, cbo, cb1, cb2, cln, d_out };
  kv_attn<<<Bb, 256, 0, stream>>>(kp);
}